// Round 1
// baseline (790.404 us; speedup 1.0000x reference)
//
#include <hip/hip_runtime.h>
#include <cstdint>
#include <cstddef>

#define NN 4096
#define DD 128

__device__ __forceinline__ float dec_f(const void* p) {
  if (!p) return 1.0f;
  int b = *(const int*)p;
  return (b >= 0 && b < 1000000) ? (float)b : __int_as_float(b);
}
__device__ __forceinline__ int dec_i(const void* p) {
  if (!p) return 4;
  int b = *(const int*)p;
  return (b >= 0 && b < 1000000) ? b : (int)__int_as_float(b);
}

// insert (v,j) into list sorted by (val desc, idx asc); caller pre-guards
template <int CAP>
__device__ __forceinline__ void ins_sorted(float (&lv)[CAP], int (&lj)[CAP], float v, int j) {
  float cv = v; int cj = j;
#pragma unroll
  for (int t = 0; t < CAP; ++t) {
    bool bt = (cv > lv[t]) || (cv == lv[t] && cj < lj[t]);
    float tv = lv[t]; int tj = lj[t];
    if (bt) { lv[t] = cv; lj[t] = cj; cv = tv; cj = tj; }
  }
}

// ---------------- K1: rowsum(A) -> rowsumA, d = rsqrt, V = d * x ----------------
__global__ __launch_bounds__(256) void k_rowsum_scale(
    const float* __restrict__ A, const float* __restrict__ x,
    float* __restrict__ rowsumA, float* __restrict__ dvec, float* __restrict__ V) {
  int row = blockIdx.x;
  int tid = threadIdx.x;
  const float4* Arow = (const float4*)(A + (size_t)row * NN);
  float s = 0.f;
#pragma unroll
  for (int l = 0; l < 4; ++l) {
    float4 v = Arow[tid + l * 256];
    s += (v.x + v.y) + (v.z + v.w);
  }
  __shared__ float red[256];
  __shared__ float dsh;
  red[tid] = s;
  __syncthreads();
  if (tid < 64) {
    s = red[tid] + red[tid + 64] + red[tid + 128] + red[tid + 192];
#pragma unroll
    for (int off = 32; off > 0; off >>= 1) s += __shfl_down(s, off, 64);
    if (tid == 0) { rowsumA[row] = s; float d = rsqrtf(s); dvec[row] = d; dsh = d; }
  }
  __syncthreads();
  float d = dsh;
  if (tid < 32) {
    float4 xv = ((const float4*)(x + (size_t)row * DD))[tid];
    float4 o; o.x = d * xv.x; o.y = d * xv.y; o.z = d * xv.z; o.w = d * xv.w;
    ((float4*)(V + (size_t)row * DD))[tid] = o;
  }
}

// ---------------- K3/K6: G_part = A[:, k-range] @ V  (+ optional sparse rows) ----------------
__global__ __launch_bounds__(256) void k_gemm_av(
    const float* __restrict__ A, const float* __restrict__ V,
    float* __restrict__ G, int ksplit,
    const int* __restrict__ sidx, const float* __restrict__ sval, const void* kptr) {
  int bx = blockIdx.x;
  int mt = bx & 63;
  int sp = bx >> 6;
  int m0 = mt * 64;
  int klen = NN / ksplit;
  int k0 = sp * klen;
  int tid = threadIdx.x;
  int tr = tid >> 4;   // 0..15 -> rows tr*4..tr*4+3
  int tc = tid & 15;   // cols tc*8..tc*8+7

  __shared__ float As[64 * 68];    // [k][m], stride 68 (16B aligned, conflict-poor)
  __shared__ float Bs[64 * 128];   // [k][c]

  float acc[4][8];
#pragma unroll
  for (int r = 0; r < 4; ++r)
#pragma unroll
    for (int c = 0; c < 8; ++c) acc[r][c] = 0.f;

  for (int kt = 0; kt < klen; kt += 64) {
    int kb = k0 + kt;
    __syncthreads();
    // stage A 64x64 -> transposed
#pragma unroll
    for (int l = 0; l < 4; ++l) {
      int idx = tid + l * 256;          // f4 units
      int r = idx >> 4;                 // 0..63
      int kq = (idx & 15) << 2;         // 0..60
      float4 a = *(const float4*)(A + (size_t)(m0 + r) * NN + kb + kq);
      As[(kq + 0) * 68 + r] = a.x;
      As[(kq + 1) * 68 + r] = a.y;
      As[(kq + 2) * 68 + r] = a.z;
      As[(kq + 3) * 68 + r] = a.w;
    }
    // stage B 64x128
#pragma unroll
    for (int l = 0; l < 8; ++l) {
      int idx = tid + l * 256;          // f4 units
      int kr = idx >> 5;                // 0..63
      int c4 = (idx & 31) << 2;         // 0..124
      *(float4*)(Bs + kr * 128 + c4) = *(const float4*)(V + (size_t)(kb + kr) * DD + c4);
    }
    __syncthreads();
#pragma unroll 8
    for (int kk = 0; kk < 64; ++kk) {
      float4 a  = *(const float4*)(As + kk * 68 + tr * 4);
      float4 b0 = *(const float4*)(Bs + kk * 128 + tc * 8);
      float4 b1 = *(const float4*)(Bs + kk * 128 + tc * 8 + 4);
      float av[4] = {a.x, a.y, a.z, a.w};
      float bv[8] = {b0.x, b0.y, b0.z, b0.w, b1.x, b1.y, b1.z, b1.w};
#pragma unroll
      for (int r = 0; r < 4; ++r)
#pragma unroll
        for (int c = 0; c < 8; ++c) acc[r][c] = fmaf(av[r], bv[c], acc[r][c]);
    }
  }

  // sparse top-k contribution (pass 2 only), added once by split 0
  if (sidx != nullptr && sp == 0) {
    int kk = dec_i(kptr); kk = kk < 1 ? 1 : (kk > 8 ? 8 : kk);
#pragma unroll
    for (int r = 0; r < 4; ++r) {
      int gr = m0 + tr * 4 + r;
      for (int t = 0; t < kk; ++t) {
        float sv = sval[gr * 8 + t];
        int id = sidx[gr * 8 + t];
        const float4* vr = (const float4*)(V + (size_t)id * DD);
        float4 w0 = vr[tc * 2];
        float4 w1 = vr[tc * 2 + 1];
        acc[r][0] = fmaf(sv, w0.x, acc[r][0]);
        acc[r][1] = fmaf(sv, w0.y, acc[r][1]);
        acc[r][2] = fmaf(sv, w0.z, acc[r][2]);
        acc[r][3] = fmaf(sv, w0.w, acc[r][3]);
        acc[r][4] = fmaf(sv, w1.x, acc[r][4]);
        acc[r][5] = fmaf(sv, w1.y, acc[r][5]);
        acc[r][6] = fmaf(sv, w1.z, acc[r][6]);
        acc[r][7] = fmaf(sv, w1.w, acc[r][7]);
      }
    }
  }

  float* Gp = G + (size_t)sp * NN * DD;
#pragma unroll
  for (int r = 0; r < 4; ++r) {
    int gr = m0 + tr * 4 + r;
    float4 o0 = {acc[r][0], acc[r][1], acc[r][2], acc[r][3]};
    float4 o1 = {acc[r][4], acc[r][5], acc[r][6], acc[r][7]};
    *(float4*)(Gp + (size_t)gr * DD + tc * 8) = o0;
    *(float4*)(Gp + (size_t)gr * DD + tc * 8 + 4) = o1;
  }
}

// ---------------- K4/K7: Out = act( d * (sum_p G_p) @ W + b ), optional sq ----------------
__global__ __launch_bounds__(256) void k_lin(
    const float* __restrict__ G, int nparts,
    const float* __restrict__ W, const float* __restrict__ bvec,
    const float* __restrict__ dvec, float* __restrict__ Out,
    int leaky, float* __restrict__ sqout) {
  int bx = blockIdx.x;
  int r0 = bx * 16;
  int tid = threadIdx.x;
  int tr = tid >> 4, tc = tid & 15;
  __shared__ float Gs[16 * 132];
  __shared__ float Ws[32 * 128];
  __shared__ float red[256];
  __shared__ float ds[16];

#pragma unroll
  for (int l = 0; l < 8; ++l) {
    int idx = tid + l * 256;   // 0..2047
    int r = idx >> 7;
    int c = idx & 127;
    float v = 0.f;
    for (int p = 0; p < nparts; ++p)
      v += G[(size_t)p * NN * DD + (size_t)(r0 + r) * DD + c];
    Gs[r * 132 + c] = v;
  }
  if (tid < 16) ds[tid] = dvec[r0 + tid];

  float acc[8];
#pragma unroll
  for (int u = 0; u < 8; ++u) acc[u] = 0.f;

  for (int t0 = 0; t0 < 128; t0 += 32) {
    __syncthreads();
#pragma unroll
    for (int l = 0; l < 4; ++l) {
      int idx = tid + l * 256;   // f4 units
      int tt = idx >> 5;
      int c4 = (idx & 31) << 2;
      *(float4*)(Ws + tt * 128 + c4) = *(const float4*)(W + (size_t)(t0 + tt) * DD + c4);
    }
    __syncthreads();
#pragma unroll 8
    for (int tt = 0; tt < 32; ++tt) {
      float g = Gs[tr * 132 + t0 + tt];
      float4 w0 = *(const float4*)(Ws + tt * 128 + tc * 8);
      float4 w1 = *(const float4*)(Ws + tt * 128 + tc * 8 + 4);
      acc[0] = fmaf(g, w0.x, acc[0]);
      acc[1] = fmaf(g, w0.y, acc[1]);
      acc[2] = fmaf(g, w0.z, acc[2]);
      acc[3] = fmaf(g, w0.w, acc[3]);
      acc[4] = fmaf(g, w1.x, acc[4]);
      acc[5] = fmaf(g, w1.y, acc[5]);
      acc[6] = fmaf(g, w1.z, acc[6]);
      acc[7] = fmaf(g, w1.w, acc[7]);
    }
  }

  float d = ds[tr];
  float4 b0 = *(const float4*)(bvec + tc * 8);
  float4 b1 = *(const float4*)(bvec + tc * 8 + 4);
  float bb[8] = {b0.x, b0.y, b0.z, b0.w, b1.x, b1.y, b1.z, b1.w};
  float o[8];
#pragma unroll
  for (int u = 0; u < 8; ++u) {
    float v = fmaf(d, acc[u], bb[u]);
    if (leaky) v = v > 0.f ? v : 0.1f * v;
    o[u] = v;
  }
  float4 o0 = {o[0], o[1], o[2], o[3]};
  float4 o1 = {o[4], o[5], o[6], o[7]};
  *(float4*)(Out + (size_t)(r0 + tr) * DD + tc * 8) = o0;
  *(float4*)(Out + (size_t)(r0 + tr) * DD + tc * 8 + 4) = o1;

  if (sqout != nullptr) {
    float p = 0.f;
#pragma unroll
    for (int u = 0; u < 8; ++u) p = fmaf(o[u], o[u], p);
    red[tid] = p;
    __syncthreads();
    if (tc == 0) {
      float s = 0.f;
#pragma unroll
      for (int i = 0; i < 16; ++i) s += red[tr * 16 + i];
      sqout[r0 + tr] = s;
    }
  }
}

// ---------------- K5: fused Z@Z^T + S + per-row partial top-8 (per j-quarter) ----------------
__global__ __launch_bounds__(256) void k_scores(
    const float* __restrict__ Z, const float* __restrict__ sq,
    float* __restrict__ pval, int* __restrict__ pidx, const void* sigptr) {
  int bx = blockIdx.x;
  int mt = bx & 63;
  int jp = bx >> 6;
  int m0 = mt * 64;
  int tid = threadIdx.x;
  int lane = tid & 63;
  int tr = tid >> 4, tc = tid & 15;
  float inv2s = 0.5f / dec_f(sigptr);

  __shared__ float Zit[128 * 68];  // [c][i], 64 rows, stride 68
  __shared__ float Zjt[64 * 68];   // [c-half][j], 64 js
  __shared__ float sqi[64];
  __shared__ float sqj[64];

#pragma unroll
  for (int l = 0; l < 8; ++l) {
    int idx = tid + l * 256;   // f4 units
    int il = idx >> 5;         // 0..63
    int c4 = (idx & 31) << 2;  // 0..124
    float4 z = *(const float4*)(Z + (size_t)(m0 + il) * DD + c4);
    Zit[(c4 + 0) * 68 + il] = z.x;
    Zit[(c4 + 1) * 68 + il] = z.y;
    Zit[(c4 + 2) * 68 + il] = z.z;
    Zit[(c4 + 3) * 68 + il] = z.w;
  }
  if (tid < 64) sqi[tid] = sq[m0 + tid];

  float myval[4][8];
  int myidx[4][8];
#pragma unroll
  for (int r = 0; r < 4; ++r)
#pragma unroll
    for (int s = 0; s < 8; ++s) { myval[r][s] = -1.f; myidx[r][s] = 0x7fffffff; }

  for (int jt = 0; jt < 16; ++jt) {
    int j0 = jp * 1024 + jt * 64;
    float acc[4][4];
#pragma unroll
    for (int r = 0; r < 4; ++r)
#pragma unroll
      for (int u = 0; u < 4; ++u) acc[r][u] = 0.f;

    for (int ch = 0; ch < 2; ++ch) {
      __syncthreads();
#pragma unroll
      for (int l = 0; l < 4; ++l) {
        int idx = tid + l * 256;   // f4 units 0..1023
        int jl = idx >> 4;         // 0..63
        int c4 = (idx & 15) << 2;  // 0..60
        float4 z = *(const float4*)(Z + (size_t)(j0 + jl) * DD + ch * 64 + c4);
        Zjt[(c4 + 0) * 68 + jl] = z.x;
        Zjt[(c4 + 1) * 68 + jl] = z.y;
        Zjt[(c4 + 2) * 68 + jl] = z.z;
        Zjt[(c4 + 3) * 68 + jl] = z.w;
      }
      if (ch == 0 && tid < 64) sqj[tid] = sq[j0 + tid];
      __syncthreads();
      int cb = ch * 64;
#pragma unroll 8
      for (int c = 0; c < 64; ++c) {
        float4 zi = *(const float4*)(Zit + (cb + c) * 68 + tr * 4);
        float4 zj = *(const float4*)(Zjt + c * 68 + tc * 4);
        float iv[4] = {zi.x, zi.y, zi.z, zi.w};
        float jv[4] = {zj.x, zj.y, zj.z, zj.w};
#pragma unroll
        for (int r = 0; r < 4; ++r)
#pragma unroll
          for (int u = 0; u < 4; ++u) acc[r][u] = fmaf(iv[r], jv[u], acc[r][u]);
      }
    }
    // scores + per-thread top-8
#pragma unroll
    for (int r = 0; r < 4; ++r) {
      float sv = sqi[tr * 4 + r];
#pragma unroll
      for (int u = 0; u < 4; ++u) {
        int jg = j0 + tc * 4 + u;
        float d2 = sv + sqj[tc * 4 + u] - 2.f * acc[r][u];
        d2 = fmaxf(d2, 0.f) + 1e-10f;
        float s = __expf(-sqrtf(d2) * inv2s);
        if (s > myval[r][7] || (s == myval[r][7] && jg < myidx[r][7]))
          ins_sorted<8>(myval[r], myidx[r], s, jg);
      }
    }
  }

  // merge across the 16 lanes sharing each row group (in-wave shuffles)
  int baselane = lane & 0x30;
#pragma unroll
  for (int r = 0; r < 4; ++r) {
    float fv[8]; int fj[8];
#pragma unroll
    for (int s = 0; s < 8; ++s) { fv[s] = -1.f; fj[s] = 0x7fffffff; }
    for (int src = 0; src < 16; ++src) {
#pragma unroll
      for (int s = 0; s < 8; ++s) {
        float v = __shfl(myval[r][s], baselane + src, 64);
        int j = __shfl(myidx[r][s], baselane + src, 64);
        if (v > fv[7] || (v == fv[7] && j < fj[7])) ins_sorted<8>(fv, fj, v, j);
      }
    }
    if (tc == 0) {
      int gr = m0 + tr * 4 + r;
#pragma unroll
      for (int s = 0; s < 8; ++s) {
        pval[((size_t)gr * 4 + jp) * 8 + s] = fv[s];
        pidx[((size_t)gr * 4 + jp) * 8 + s] = fj[s];
      }
    }
  }
}

// ---------------- K5b: merge partial lists, d2 = rsqrt(rowsumA + sum S), V = d2*x ----------------
__global__ __launch_bounds__(256) void k_merge(
    const float* __restrict__ pval, const int* __restrict__ pidx,
    const float* __restrict__ rowsumA, const float* __restrict__ x,
    float* __restrict__ sval, int* __restrict__ sidx,
    float* __restrict__ d2vec, float* __restrict__ V, const void* kptr) {
  int bx = blockIdx.x;
  int r0 = bx * 16;
  int tid = threadIdx.x;
  int kk = dec_i(kptr); kk = kk < 1 ? 1 : (kk > 8 ? 8 : kk);
  __shared__ float ds[16];
  if (tid < 16) {
    int r = r0 + tid;
    float fv[8]; int fj[8];
#pragma unroll
    for (int s = 0; s < 8; ++s) { fv[s] = -1.f; fj[s] = 0x7fffffff; }
#pragma unroll
    for (int p = 0; p < 4; ++p) {
#pragma unroll
      for (int s = 0; s < 8; ++s) {
        float v = pval[((size_t)r * 4 + p) * 8 + s];
        int j = pidx[((size_t)r * 4 + p) * 8 + s];
        if (v > fv[7] || (v == fv[7] && j < fj[7])) ins_sorted<8>(fv, fj, v, j);
      }
    }
    float srow = 0.f;
#pragma unroll
    for (int s = 0; s < 8; ++s) if (s < kk) srow += fv[s];
    float dd = rsqrtf(rowsumA[r] + srow);
    d2vec[r] = dd;
    ds[tid] = dd;
#pragma unroll
    for (int s = 0; s < 8; ++s) if (s < kk) { sval[r * 8 + s] = fv[s]; sidx[r * 8 + s] = fj[s]; }
  }
  __syncthreads();
#pragma unroll
  for (int l = 0; l < 2; ++l) {
    int idx = tid + l * 256;   // f4 units 0..511
    int rl = idx >> 5;         // 0..15
    int c4 = (idx & 31) << 2;
    float4 xv = *(const float4*)(x + (size_t)(r0 + rl) * DD + c4);
    float dd = ds[rl];
    float4 o; o.x = dd * xv.x; o.y = dd * xv.y; o.z = dd * xv.z; o.w = dd * xv.w;
    *(float4*)(V + (size_t)(r0 + rl) * DD + c4) = o;
  }
}

extern "C" void kernel_launch(void* const* d_in, const int* in_sizes, int n_in,
                              void* d_out, int out_size, void* d_ws, size_t ws_size,
                              hipStream_t stream) {
  const float* x  = (const float*)d_in[0];
  const float* A  = (const float*)d_in[1];
  const float* W1 = (const float*)d_in[2];
  const float* b1 = (const float*)d_in[3];
  const float* W2 = (const float*)d_in[4];
  const float* b2 = (const float*)d_in[5];
  const void* sig = (n_in > 6) ? d_in[6] : nullptr;
  const void* kp  = (n_in > 7) ? d_in[7] : nullptr;

  float* ws = (float*)d_ws;
  float* rowsumA = ws;                    // 4096
  float* dvec    = ws + 4096;             // 4096
  float* d2vec   = ws + 8192;             // 4096
  float* sq      = ws + 12288;            // 4096
  float* sval    = ws + 16384;            // 32768
  int*   sidx    = (int*)(ws + 49152);    // 32768
  float* pval    = ws + 81920;            // 131072
  int*   pidx    = (int*)(ws + 212992);   // 131072
  float* V       = ws + 344064;           // 524288
  float* Z       = ws + 868352;           // 524288
  float* G       = ws + 1392640;          // 524288 * ksplit

  const size_t base_floats = 1392640;
  const size_t nd = (size_t)NN * DD;
  int ksplit = 4;
  if (ws_size < (base_floats + 4 * nd) * 4) ksplit = 2;
  if (ws_size < (base_floats + 2 * nd) * 4) ksplit = 1;

  // pass 1: laplacian matmul
  k_rowsum_scale<<<NN, 256, 0, stream>>>(A, x, rowsumA, dvec, V);
  k_gemm_av<<<64 * ksplit, 256, 0, stream>>>(A, V, G, ksplit, nullptr, nullptr, nullptr);
  k_lin<<<256, 256, 0, stream>>>(G, ksplit, W1, b1, dvec, Z, 1, sq);
  // pairwise scores + top-k
  k_scores<<<256, 256, 0, stream>>>(Z, sq, pval, pidx, sig);
  k_merge<<<256, 256, 0, stream>>>(pval, pidx, rowsumA, x, sval, sidx, d2vec, V, kp);
  // pass 2: laplacian matmul on A + sparse S
  k_gemm_av<<<64 * ksplit, 256, 0, stream>>>(A, V, G, ksplit, sidx, sval, kp);
  k_lin<<<256, 256, 0, stream>>>(G, ksplit, W2, b2, d2vec, (float*)d_out, 0, nullptr);
}

// Round 2
// 469.932 us; speedup vs baseline: 1.6820x; 1.6820x over previous
//
#include <hip/hip_runtime.h>
#include <cstdint>
#include <cstddef>

#define NN 4096
#define DD 128

using short8 = __attribute__((ext_vector_type(8))) short;
using f32x4  = __attribute__((ext_vector_type(4))) float;

__device__ __forceinline__ float dec_f(const void* p) {
  if (!p) return 1.0f;
  int b = *(const int*)p;
  return (b >= 0 && b < 1000000) ? (float)b : __int_as_float(b);
}
__device__ __forceinline__ int dec_i(const void* p) {
  if (!p) return 4;
  int b = *(const int*)p;
  return (b >= 0 && b < 1000000) ? b : (int)__int_as_float(b);
}

__device__ __forceinline__ unsigned short f2bf(float f) {
  union { float f; unsigned int u; } v; v.f = f;
  unsigned int u = v.u;
  unsigned int r = (u + 0x7fffu + ((u >> 16) & 1u)) >> 16;
  return (unsigned short)r;
}
__device__ __forceinline__ float bf2f(unsigned short h) {
  union { unsigned int u; float f; } v; v.u = ((unsigned int)h) << 16;
  return v.f;
}

// descending by (val desc, idx asc)
template <int CAP>
__device__ __forceinline__ void ins_desc(float (&lv)[CAP], int (&lj)[CAP], float v, int j) {
  float cv = v; int cj = j;
#pragma unroll
  for (int t = 0; t < CAP; ++t) {
    bool bt = (cv > lv[t]) || (cv == lv[t] && cj < lj[t]);
    float tv = lv[t]; int tj = lj[t];
    if (bt) { lv[t] = cv; lj[t] = cj; cv = tv; cj = tj; }
  }
}
// ascending by (key asc, idx asc)  (key = clamped d^2)
template <int CAP>
__device__ __forceinline__ void ins_asc(float (&lv)[CAP], int (&lj)[CAP], float v, int j) {
  float cv = v; int cj = j;
#pragma unroll
  for (int t = 0; t < CAP; ++t) {
    bool bt = (cv < lv[t]) || (cv == lv[t] && cj < lj[t]);
    float tv = lv[t]; int tj = lj[t];
    if (bt) { lv[t] = cv; lj[t] = cj; cv = tv; cj = tj; }
  }
}

// ---------------- K1: rowsum(A) -> rowsumA, d = rsqrt, V = d * x ----------------
__global__ __launch_bounds__(256) void k_rowsum_scale(
    const float* __restrict__ A, const float* __restrict__ x,
    float* __restrict__ rowsumA, float* __restrict__ dvec, float* __restrict__ V) {
  int row = blockIdx.x;
  int tid = threadIdx.x;
  const float4* Arow = (const float4*)(A + (size_t)row * NN);
  float s = 0.f;
#pragma unroll
  for (int l = 0; l < 4; ++l) {
    float4 v = Arow[tid + l * 256];
    s += (v.x + v.y) + (v.z + v.w);
  }
  __shared__ float red[256];
  __shared__ float dsh;
  red[tid] = s;
  __syncthreads();
  if (tid < 64) {
    s = red[tid] + red[tid + 64] + red[tid + 128] + red[tid + 192];
#pragma unroll
    for (int off = 32; off > 0; off >>= 1) s += __shfl_down(s, off, 64);
    if (tid == 0) { rowsumA[row] = s; float d = rsqrtf(s); dvec[row] = d; dsh = d; }
  }
  __syncthreads();
  float d = dsh;
  if (tid < 32) {
    float4 xv = ((const float4*)(x + (size_t)row * DD))[tid];
    float4 o; o.x = d * xv.x; o.y = d * xv.y; o.z = d * xv.z; o.w = d * xv.w;
    ((float4*)(V + (size_t)row * DD))[tid] = o;
  }
}

// ---------------- K3/K6: G_part = A[:, k-range] @ V  (+ optional sparse rows) ----------------
__global__ __launch_bounds__(256) void k_gemm_av(
    const float* __restrict__ A, const float* __restrict__ V,
    float* __restrict__ G, int ksplit,
    const int* __restrict__ sidx, const float* __restrict__ sval, const void* kptr) {
  int bx = blockIdx.x;
  int mt = bx & 63;
  int sp = bx >> 6;
  int m0 = mt * 64;
  int klen = NN / ksplit;
  int k0 = sp * klen;
  int tid = threadIdx.x;
  int tr = tid >> 4;
  int tc = tid & 15;

  __shared__ float As[64 * 68];
  __shared__ float Bs[64 * 128];

  float acc[4][8];
#pragma unroll
  for (int r = 0; r < 4; ++r)
#pragma unroll
    for (int c = 0; c < 8; ++c) acc[r][c] = 0.f;

  for (int kt = 0; kt < klen; kt += 64) {
    int kb = k0 + kt;
    __syncthreads();
#pragma unroll
    for (int l = 0; l < 4; ++l) {
      int idx = tid + l * 256;
      int r = idx >> 4;
      int kq = (idx & 15) << 2;
      float4 a = *(const float4*)(A + (size_t)(m0 + r) * NN + kb + kq);
      As[(kq + 0) * 68 + r] = a.x;
      As[(kq + 1) * 68 + r] = a.y;
      As[(kq + 2) * 68 + r] = a.z;
      As[(kq + 3) * 68 + r] = a.w;
    }
#pragma unroll
    for (int l = 0; l < 8; ++l) {
      int idx = tid + l * 256;
      int kr = idx >> 5;
      int c4 = (idx & 31) << 2;
      *(float4*)(Bs + kr * 128 + c4) = *(const float4*)(V + (size_t)(kb + kr) * DD + c4);
    }
    __syncthreads();
#pragma unroll 8
    for (int kk = 0; kk < 64; ++kk) {
      float4 a  = *(const float4*)(As + kk * 68 + tr * 4);
      float4 b0 = *(const float4*)(Bs + kk * 128 + tc * 8);
      float4 b1 = *(const float4*)(Bs + kk * 128 + tc * 8 + 4);
      float av[4] = {a.x, a.y, a.z, a.w};
      float bv[8] = {b0.x, b0.y, b0.z, b0.w, b1.x, b1.y, b1.z, b1.w};
#pragma unroll
      for (int r = 0; r < 4; ++r)
#pragma unroll
        for (int c = 0; c < 8; ++c) acc[r][c] = fmaf(av[r], bv[c], acc[r][c]);
    }
  }

  if (sidx != nullptr && sp == 0) {
    int kk = dec_i(kptr); kk = kk < 1 ? 1 : (kk > 8 ? 8 : kk);
#pragma unroll
    for (int r = 0; r < 4; ++r) {
      int gr = m0 + tr * 4 + r;
      for (int t = 0; t < kk; ++t) {
        float sv = sval[gr * 8 + t];
        int id = sidx[gr * 8 + t];
        const float4* vr = (const float4*)(V + (size_t)id * DD);
        float4 w0 = vr[tc * 2];
        float4 w1 = vr[tc * 2 + 1];
        acc[r][0] = fmaf(sv, w0.x, acc[r][0]);
        acc[r][1] = fmaf(sv, w0.y, acc[r][1]);
        acc[r][2] = fmaf(sv, w0.z, acc[r][2]);
        acc[r][3] = fmaf(sv, w0.w, acc[r][3]);
        acc[r][4] = fmaf(sv, w1.x, acc[r][4]);
        acc[r][5] = fmaf(sv, w1.y, acc[r][5]);
        acc[r][6] = fmaf(sv, w1.z, acc[r][6]);
        acc[r][7] = fmaf(sv, w1.w, acc[r][7]);
      }
    }
  }

  float* Gp = G + (size_t)sp * NN * DD;
#pragma unroll
  for (int r = 0; r < 4; ++r) {
    int gr = m0 + tr * 4 + r;
    float4 o0 = {acc[r][0], acc[r][1], acc[r][2], acc[r][3]};
    float4 o1 = {acc[r][4], acc[r][5], acc[r][6], acc[r][7]};
    *(float4*)(Gp + (size_t)gr * DD + tc * 8) = o0;
    *(float4*)(Gp + (size_t)gr * DD + tc * 8 + 4) = o1;
  }
}

// ---- K4/K7: Out = act( d * (sum_p G_p) @ W + b ); optional sq, optional bf16 hi/lo split ----
__global__ __launch_bounds__(256) void k_lin(
    const float* __restrict__ G, int nparts,
    const float* __restrict__ W, const float* __restrict__ bvec,
    const float* __restrict__ dvec, float* __restrict__ Out,
    int leaky, float* __restrict__ sqout,
    unsigned short* __restrict__ zh, unsigned short* __restrict__ zl) {
  int bx = blockIdx.x;
  int r0 = bx * 16;
  int tid = threadIdx.x;
  int tr = tid >> 4, tc = tid & 15;
  __shared__ float Gs[16 * 132];
  __shared__ float Ws[32 * 128];
  __shared__ float red[256];
  __shared__ float ds[16];

#pragma unroll
  for (int l = 0; l < 8; ++l) {
    int idx = tid + l * 256;
    int r = idx >> 7;
    int c = idx & 127;
    float v = 0.f;
    for (int p = 0; p < nparts; ++p)
      v += G[(size_t)p * NN * DD + (size_t)(r0 + r) * DD + c];
    Gs[r * 132 + c] = v;
  }
  if (tid < 16) ds[tid] = dvec[r0 + tid];

  float acc[8];
#pragma unroll
  for (int u = 0; u < 8; ++u) acc[u] = 0.f;

  for (int t0 = 0; t0 < 128; t0 += 32) {
    __syncthreads();
#pragma unroll
    for (int l = 0; l < 4; ++l) {
      int idx = tid + l * 256;
      int tt = idx >> 5;
      int c4 = (idx & 31) << 2;
      *(float4*)(Ws + tt * 128 + c4) = *(const float4*)(W + (size_t)(t0 + tt) * DD + c4);
    }
    __syncthreads();
#pragma unroll 8
    for (int tt = 0; tt < 32; ++tt) {
      float g = Gs[tr * 132 + t0 + tt];
      float4 w0 = *(const float4*)(Ws + tt * 128 + tc * 8);
      float4 w1 = *(const float4*)(Ws + tt * 128 + tc * 8 + 4);
      acc[0] = fmaf(g, w0.x, acc[0]);
      acc[1] = fmaf(g, w0.y, acc[1]);
      acc[2] = fmaf(g, w0.z, acc[2]);
      acc[3] = fmaf(g, w0.w, acc[3]);
      acc[4] = fmaf(g, w1.x, acc[4]);
      acc[5] = fmaf(g, w1.y, acc[5]);
      acc[6] = fmaf(g, w1.z, acc[6]);
      acc[7] = fmaf(g, w1.w, acc[7]);
    }
  }

  float d = ds[tr];
  float4 b0 = *(const float4*)(bvec + tc * 8);
  float4 b1 = *(const float4*)(bvec + tc * 8 + 4);
  float bb[8] = {b0.x, b0.y, b0.z, b0.w, b1.x, b1.y, b1.z, b1.w};
  float o[8];
#pragma unroll
  for (int u = 0; u < 8; ++u) {
    float v = fmaf(d, acc[u], bb[u]);
    if (leaky) v = v > 0.f ? v : 0.1f * v;
    o[u] = v;
  }
  size_t rowoff = (size_t)(r0 + tr) * DD + tc * 8;
  if (Out) {
    float4 o0 = {o[0], o[1], o[2], o[3]};
    float4 o1 = {o[4], o[5], o[6], o[7]};
    *(float4*)(Out + rowoff) = o0;
    *(float4*)(Out + rowoff + 4) = o1;
  }
  if (zh) {
    unsigned short hb[8], lb[8];
#pragma unroll
    for (int u = 0; u < 8; ++u) {
      hb[u] = f2bf(o[u]);
      lb[u] = f2bf(o[u] - bf2f(hb[u]));
    }
    ushort4 h0 = {hb[0], hb[1], hb[2], hb[3]};
    ushort4 h1 = {hb[4], hb[5], hb[6], hb[7]};
    ushort4 l0 = {lb[0], lb[1], lb[2], lb[3]};
    ushort4 l1 = {lb[4], lb[5], lb[6], lb[7]};
    *(ushort4*)(zh + rowoff) = h0;
    *(ushort4*)(zh + rowoff + 4) = h1;
    *(ushort4*)(zl + rowoff) = l0;
    *(ushort4*)(zl + rowoff + 4) = l1;
  }

  if (sqout != nullptr) {
    float p = 0.f;
#pragma unroll
    for (int u = 0; u < 8; ++u) p = fmaf(o[u], o[u], p);
    red[tid] = p;
    __syncthreads();
    if (tc == 0) {
      float s = 0.f;
#pragma unroll
      for (int i = 0; i < 16; ++i) s += red[tr * 16 + i];
      sqout[r0 + tr] = s;
    }
  }
}

// ---- K5: MFMA split-bf16 Z@Z^T (3 terms, K=384), fused d2 + per-row partial top-8 ----
// grid: 32 m-tiles x 16 j-partitions; block 128 rows x 256 cols (2 j-tiles of 128)
__global__ __launch_bounds__(256, 2) void k_scores(
    const unsigned short* __restrict__ Zh, const unsigned short* __restrict__ Zl,
    const float* __restrict__ sq,
    float* __restrict__ pval, int* __restrict__ pidx, const void* sigptr) {
  int bx = blockIdx.x;
  int mt = bx >> 4;
  int jp = bx & 15;
  int m0 = mt * 128;
  int j0 = jp * 256;
  int tid = threadIdx.x;
  int lane = tid & 63;
  int w = tid >> 6;
  int wm = w >> 1, wn = w & 1;
  float inv2s = 0.5f / dec_f(sigptr);

  __shared__ __align__(16) unsigned short As[128 * 64];
  __shared__ __align__(16) unsigned short Bs[128 * 64];
  __shared__ __align__(16) float Stile[64 * 132];
  __shared__ float sqi_s[128];
  __shared__ float sqj_s[256];

  if (tid < 128) sqi_s[tid] = sq[m0 + tid];
  sqj_s[tid] = sq[j0 + tid];
  __syncthreads();

  const unsigned short* segAp[3] = {Zh, Zh, Zl};
  const unsigned short* segBp[3] = {Zh, Zl, Zh};

  int r = tid >> 1;            // scan row 0..127
  int cseg = (tid & 1) << 5;   // scan col segment (0 or 32) within 64-half
  float sqi_r = sqi_s[r];

  float lv[8]; int lj[8];
#pragma unroll
  for (int s = 0; s < 8; ++s) { lv[s] = 3.4e38f; lj[s] = 0x7fffffff; }

  for (int jt = 0; jt < 2; ++jt) {
    int jrow0 = j0 + jt * 128;
    f32x4 acc[4][4];
#pragma unroll
    for (int fm = 0; fm < 4; ++fm)
#pragma unroll
      for (int fn = 0; fn < 4; ++fn) acc[fm][fn] = (f32x4){0.f, 0.f, 0.f, 0.f};

    for (int seg = 0; seg < 3; ++seg) {
      const unsigned short* sa = segAp[seg];
      const unsigned short* sb = segBp[seg];
      for (int kh = 0; kh < 2; ++kh) {
        int kb = kh * 64;
        __syncthreads();
        // stage 128x64 bf16 tiles, XOR-swizzled 16B blocks (2-way LDS aliasing = free)
#pragma unroll
        for (int l = 0; l < 4; ++l) {
          int u = tid + l * 256;          // 16B unit 0..1023
          int rw = u >> 3;                // row 0..127
          int pb = u & 7;                 // physical block
          int lb = pb ^ (rw & 7);         // logical block
          ((uint4*)As)[u] = *(const uint4*)(sa + (size_t)(m0 + rw) * DD + kb + lb * 8);
          ((uint4*)Bs)[u] = *(const uint4*)(sb + (size_t)(jrow0 + rw) * DD + kb + lb * 8);
        }
        __syncthreads();
#pragma unroll
        for (int k0 = 0; k0 < 64; k0 += 32) {
          short8 af[4], bfr[4];
          int la = (k0 >> 3) + (lane >> 4);
#pragma unroll
          for (int f = 0; f < 4; ++f) {
            int ra = wm * 64 + f * 16 + (lane & 15);
            af[f] = *(const short8*)(As + ra * 64 + (la ^ (ra & 7)) * 8);
            int rb = wn * 64 + f * 16 + (lane & 15);
            bfr[f] = *(const short8*)(Bs + rb * 64 + (la ^ (rb & 7)) * 8);
          }
#pragma unroll
          for (int fm = 0; fm < 4; ++fm)
#pragma unroll
            for (int fn = 0; fn < 4; ++fn)
              acc[fm][fn] = __builtin_amdgcn_mfma_f32_16x16x32_bf16(af[fm], bfr[fn], acc[fm][fn], 0, 0, 0);
        }
      }
    }

    // epilogue: two 64-col halves through LDS (col-major), scan for top-8 by d2 asc
    for (int h = 0; h < 2; ++h) {
      __syncthreads();
      if (wn == h) {
        int quad = lane >> 4;
#pragma unroll
        for (int fm = 0; fm < 4; ++fm)
#pragma unroll
          for (int fn = 0; fn < 4; ++fn) {
            int colL = fn * 16 + (lane & 15);
            float sqjv = sqj_s[jt * 128 + h * 64 + colL];
            f32x4 a = acc[fm][fn];
            float4 vv = {fmaf(-2.f, a[0], sqjv), fmaf(-2.f, a[1], sqjv),
                         fmaf(-2.f, a[2], sqjv), fmaf(-2.f, a[3], sqjv)};
            *(float4*)(&Stile[colL * 132 + wm * 64 + fm * 16 + quad * 4]) = vv;
          }
      }
      __syncthreads();
      int jbase = j0 + jt * 128 + h * 64;
#pragma unroll 4
      for (int c = 0; c < 32; ++c) {
        int colL = cseg + c;
        float t = Stile[colL * 132 + r];
        float d2 = fmaxf(sqi_r + t, 0.f);
        int jg = jbase + colL;
        if (d2 < lv[7] || (d2 == lv[7] && jg < lj[7])) ins_asc<8>(lv, lj, d2, jg);
      }
    }
  }

  // merge with partner thread (other half of this row's cols), then convert kept d2 -> S
  float tv[8]; int tj[8];
  int pl = lane ^ 1;
#pragma unroll
  for (int s = 0; s < 8; ++s) { tv[s] = __shfl(lv[s], pl, 64); tj[s] = __shfl(lj[s], pl, 64); }
#pragma unroll
  for (int s = 0; s < 8; ++s)
    if (tv[s] < lv[7] || (tv[s] == lv[7] && tj[s] < lj[7])) ins_asc<8>(lv, lj, tv[s], tj[s]);
  if ((tid & 1) == 0) {
    int grow = m0 + r;
#pragma unroll
    for (int s = 0; s < 8; ++s) {
      pval[((size_t)grow * 16 + jp) * 8 + s] = __expf(-sqrtf(lv[s] + 1e-10f) * inv2s);
      pidx[((size_t)grow * 16 + jp) * 8 + s] = lj[s];
    }
  }
}

// ---- K5b: merge 16 partial lists, d2 = rsqrt(rowsumA + sum S), V = d2*x ----
__global__ __launch_bounds__(256) void k_merge(
    const float* __restrict__ pval, const int* __restrict__ pidx,
    const float* __restrict__ rowsumA, const float* __restrict__ x,
    float* __restrict__ sval, int* __restrict__ sidx,
    float* __restrict__ d2vec, float* __restrict__ V, const void* kptr) {
  int bx = blockIdx.x;
  int r0 = bx * 16;
  int tid = threadIdx.x;
  int kk = dec_i(kptr); kk = kk < 1 ? 1 : (kk > 8 ? 8 : kk);
  __shared__ float ds[16];
  if (tid < 16) {
    int r = r0 + tid;
    float fv[8]; int fj[8];
#pragma unroll
    for (int s = 0; s < 8; ++s) { fv[s] = -1.f; fj[s] = 0x7fffffff; }
    for (int p = 0; p < 16; ++p) {
#pragma unroll
      for (int s = 0; s < 8; ++s) {
        float v = pval[((size_t)r * 16 + p) * 8 + s];
        int j = pidx[((size_t)r * 16 + p) * 8 + s];
        if (v > fv[7] || (v == fv[7] && j < fj[7])) ins_desc<8>(fv, fj, v, j);
      }
    }
    float srow = 0.f;
#pragma unroll
    for (int s = 0; s < 8; ++s) if (s < kk) srow += fv[s];
    float dd = rsqrtf(rowsumA[r] + srow);
    d2vec[r] = dd;
    ds[tid] = dd;
#pragma unroll
    for (int s = 0; s < 8; ++s) if (s < kk) { sval[r * 8 + s] = fv[s]; sidx[r * 8 + s] = fj[s]; }
  }
  __syncthreads();
#pragma unroll
  for (int l = 0; l < 2; ++l) {
    int idx = tid + l * 256;
    int rl = idx >> 5;
    int c4 = (idx & 31) << 2;
    float4 xv = *(const float4*)(x + (size_t)(r0 + rl) * DD + c4);
    float dd = ds[rl];
    float4 o; o.x = dd * xv.x; o.y = dd * xv.y; o.z = dd * xv.z; o.w = dd * xv.w;
    *(float4*)(V + (size_t)(r0 + rl) * DD + c4) = o;
  }
}

extern "C" void kernel_launch(void* const* d_in, const int* in_sizes, int n_in,
                              void* d_out, int out_size, void* d_ws, size_t ws_size,
                              hipStream_t stream) {
  const float* x  = (const float*)d_in[0];
  const float* A  = (const float*)d_in[1];
  const float* W1 = (const float*)d_in[2];
  const float* b1 = (const float*)d_in[3];
  const float* W2 = (const float*)d_in[4];
  const float* b2 = (const float*)d_in[5];
  const void* sig = (n_in > 6) ? d_in[6] : nullptr;
  const void* kp  = (n_in > 7) ? d_in[7] : nullptr;

  float* ws = (float*)d_ws;
  float* rowsumA = ws;                               // 4096
  float* dvec    = ws + 4096;                        // 4096
  float* d2vec   = ws + 8192;                        // 4096
  float* sq      = ws + 12288;                       // 4096
  float* sval    = ws + 16384;                       // 32768
  int*   sidx    = (int*)(ws + 49152);               // 32768
  float* pval    = ws + 81920;                       // 4096*16*8 = 524288
  int*   pidx    = (int*)(ws + 606208);              // 524288
  unsigned short* Zh = (unsigned short*)(ws + 1130496);  // 262144 floats
  unsigned short* Zl = (unsigned short*)(ws + 1392640);  // 262144 floats
  float* V       = ws + 1654784;                     // 524288
  float* G       = ws + 2179072;                     // ksplit * 524288

  const size_t base_floats = 2179072;
  const size_t nd = (size_t)NN * DD;
  int ksplit = 4;
  if (ws_size < (base_floats + 4 * nd) * 4) ksplit = 2;
  if (ws_size < (base_floats + 2 * nd) * 4) ksplit = 1;

  // pass 1: laplacian matmul + linear1 + leaky relu (emits bf16 hi/lo split of Z and ||z||^2)
  k_rowsum_scale<<<NN, 256, 0, stream>>>(A, x, rowsumA, dvec, V);
  k_gemm_av<<<64 * ksplit, 256, 0, stream>>>(A, V, G, ksplit, nullptr, nullptr, nullptr);
  k_lin<<<256, 256, 0, stream>>>(G, ksplit, W1, b1, dvec, nullptr, 1, sq, Zh, Zl);
  // pairwise scores (MFMA split-bf16) + top-k
  k_scores<<<512, 256, 0, stream>>>(Zh, Zl, sq, pval, pidx, sig);
  k_merge<<<256, 256, 0, stream>>>(pval, pidx, rowsumA, x, sval, sidx, d2vec, V, kp);
  // pass 2: laplacian matmul on A + sparse S
  k_gemm_av<<<64 * ksplit, 256, 0, stream>>>(A, V, G, ksplit, sidx, sval, kp);
  k_lin<<<256, 256, 0, stream>>>(G, ksplit, W2, b2, d2vec, (float*)d_out, 0, nullptr, nullptr, nullptr);
}

// Round 3
// 413.272 us; speedup vs baseline: 1.9126x; 1.1371x over previous
//
#include <hip/hip_runtime.h>
#include <cstdint>
#include <cstddef>

#define NN 4096
#define DD 128

using short8 = __attribute__((ext_vector_type(8))) short;
using f32x4  = __attribute__((ext_vector_type(4))) float;

typedef __attribute__((address_space(1))) void gvoid;
typedef __attribute__((address_space(3))) void lvoid;

__device__ __forceinline__ void async16(const void* g, void* l) {
  __builtin_amdgcn_global_load_lds((gvoid*)g, (lvoid*)l, 16, 0, 0);
}

__device__ __forceinline__ float dec_f(const void* p) {
  if (!p) return 1.0f;
  int b = *(const int*)p;
  return (b >= 0 && b < 1000000) ? (float)b : __int_as_float(b);
}
__device__ __forceinline__ int dec_i(const void* p) {
  if (!p) return 4;
  int b = *(const int*)p;
  return (b >= 0 && b < 1000000) ? b : (int)__int_as_float(b);
}

__device__ __forceinline__ unsigned short f2bf(float f) {
  union { float f; unsigned int u; } v; v.f = f;
  unsigned int u = v.u;
  unsigned int r = (u + 0x7fffu + ((u >> 16) & 1u)) >> 16;
  return (unsigned short)r;
}
__device__ __forceinline__ float bf2f(unsigned short h) {
  union { unsigned int u; float f; } v; v.u = ((unsigned int)h) << 16;
  return v.f;
}

// descending by (val desc, idx asc)
template <int CAP>
__device__ __forceinline__ void ins_desc(float (&lv)[CAP], int (&lj)[CAP], float v, int j) {
  float cv = v; int cj = j;
#pragma unroll
  for (int t = 0; t < CAP; ++t) {
    bool bt = (cv > lv[t]) || (cv == lv[t] && cj < lj[t]);
    float tv = lv[t]; int tj = lj[t];
    if (bt) { lv[t] = cv; lj[t] = cj; cv = tv; cj = tj; }
  }
}
// ascending by (key asc, idx asc)  (key = clamped d^2)
template <int CAP>
__device__ __forceinline__ void ins_asc(float (&lv)[CAP], int (&lj)[CAP], float v, int j) {
  float cv = v; int cj = j;
#pragma unroll
  for (int t = 0; t < CAP; ++t) {
    bool bt = (cv < lv[t]) || (cv == lv[t] && cj < lj[t]);
    float tv = lv[t]; int tj = lj[t];
    if (bt) { lv[t] = cv; lj[t] = cj; cv = tv; cj = tj; }
  }
}

// stage a ROWS x 64 bf16 tile into LDS via global_load_lds (16B/lane),
// LDS layout: row*64 ushorts, 16B chunk p holds logical chunk p ^ (row&7)
template <int ROWS>
__device__ __forceinline__ void stage_tile(const unsigned short* src, int row0, int kb,
                                           unsigned short* dst, int tid, int srcstride) {
  int lane = tid & 63, w = tid >> 6;
  const int rpw = ROWS / 4;
  const int ipw = rpw / 8;
#pragma unroll
  for (int i = 0; i < ipw; ++i) {
    int rb = w * rpw + i * 8;
    int r = rb + (lane >> 3);
    int ch = (lane & 7) ^ (r & 7);
    const void* g = src + (size_t)(row0 + r) * srcstride + kb + ch * 8;
    async16(g, dst + rb * 64);
  }
}

__device__ __forceinline__ short8 frag(const unsigned short* t, int row, int ch) {
  return *(const short8*)(t + row * 64 + ((ch ^ (row & 7)) << 3));
}

// ---------------- K1: rowsum(A), d = rsqrt, V = d*x, A -> bf16 hi/lo ----------------
__global__ __launch_bounds__(256) void k_rowsum_scale(
    const float* __restrict__ A, const float* __restrict__ x,
    float* __restrict__ rowsumA, float* __restrict__ dvec, float* __restrict__ V,
    unsigned short* __restrict__ Ah, unsigned short* __restrict__ Al) {
  int row = blockIdx.x;
  int tid = threadIdx.x;
  const float4* Arow = (const float4*)(A + (size_t)row * NN);
  float s = 0.f;
#pragma unroll
  for (int l = 0; l < 4; ++l) {
    int idx = tid + l * 256;
    float4 v = Arow[idx];
    s += (v.x + v.y) + (v.z + v.w);
    if (Ah) {
      ushort4 h = {f2bf(v.x), f2bf(v.y), f2bf(v.z), f2bf(v.w)};
      *(ushort4*)(Ah + (size_t)row * NN + idx * 4) = h;
      if (Al) {
        ushort4 lo = {f2bf(v.x - bf2f(h.x)), f2bf(v.y - bf2f(h.y)),
                      f2bf(v.z - bf2f(h.z)), f2bf(v.w - bf2f(h.w))};
        *(ushort4*)(Al + (size_t)row * NN + idx * 4) = lo;
      }
    }
  }
  __shared__ float red[256];
  __shared__ float dsh;
  red[tid] = s;
  __syncthreads();
  if (tid < 64) {
    s = red[tid] + red[tid + 64] + red[tid + 128] + red[tid + 192];
#pragma unroll
    for (int off = 32; off > 0; off >>= 1) s += __shfl_down(s, off, 64);
    if (tid == 0) { rowsumA[row] = s; float d = rsqrtf(s); dvec[row] = d; dsh = d; }
  }
  __syncthreads();
  float d = dsh;
  if (tid < 32) {
    float4 xv = ((const float4*)(x + (size_t)row * DD))[tid];
    float4 o; o.x = d * xv.x; o.y = d * xv.y; o.z = d * xv.z; o.w = d * xv.w;
    ((float4*)(V + (size_t)row * DD))[tid] = o;
  }
}

// ---------------- K2: V [4096][128] fp32 -> VT [128][4096] bf16 hi(/lo) ----------------
__global__ __launch_bounds__(256) void k_vt(
    const float* __restrict__ V, unsigned short* __restrict__ VTh,
    unsigned short* __restrict__ VTl, int emit_lo) {
  __shared__ float Ls[64 * 132];
  int bx = blockIdx.x, tid = threadIdx.x;
  int r0 = bx * 64;
#pragma unroll
  for (int l = 0; l < 8; ++l) {
    int idx = tid + l * 256;
    int r = idx >> 5, c4 = (idx & 31) << 2;
    *(float4*)(Ls + r * 132 + c4) = *(const float4*)(V + (size_t)(r0 + r) * DD + c4);
  }
  __syncthreads();
  int c = tid >> 1, rh = tid & 1;
  unsigned short hb[32], lb[32];
#pragma unroll
  for (int i = 0; i < 32; ++i) {
    float v = Ls[(rh * 32 + i) * 132 + c];
    hb[i] = f2bf(v);
    lb[i] = f2bf(v - bf2f(hb[i]));
  }
  size_t base = (size_t)c * NN + r0 + rh * 32;
#pragma unroll
  for (int q = 0; q < 8; ++q) {
    ushort4 h = {hb[q * 4], hb[q * 4 + 1], hb[q * 4 + 2], hb[q * 4 + 3]};
    *(ushort4*)(VTh + base + q * 4) = h;
  }
  if (emit_lo) {
#pragma unroll
    for (int q = 0; q < 8; ++q) {
      ushort4 lo = {lb[q * 4], lb[q * 4 + 1], lb[q * 4 + 2], lb[q * 4 + 3]};
      *(ushort4*)(VTl + base + q * 4) = lo;
    }
  }
}

// ---------------- K3/K6: MFMA bf16 GEMM  G_part = A[128 rows][256 k] @ V ----------------
// grid 512: mt = bx>>4 (32), sp = bx&15 (16 k-splits); block 256 thr, 4 waves 2x2, 64x64/wave
template <int TERMS>
__global__ __launch_bounds__(256) void k_gemm_bf16(
    const unsigned short* __restrict__ Ah, const unsigned short* __restrict__ Al,
    const unsigned short* __restrict__ Bh, const unsigned short* __restrict__ Bl,
    float* __restrict__ G) {
  __shared__ __align__(16) unsigned short As_h[128 * 64];
  __shared__ __align__(16) unsigned short Bs_h[128 * 64];
  __shared__ __align__(16) unsigned short As_l[TERMS == 3 ? 128 * 64 : 8];
  __shared__ __align__(16) unsigned short Bs_l[TERMS == 3 ? 128 * 64 : 8];

  int bx = blockIdx.x;
  int mt = bx >> 4, sp = bx & 15;
  int m0 = mt * 128;
  int ks = sp * 256;
  int tid = threadIdx.x, lane = tid & 63, w = tid >> 6;
  int wm = w >> 1, wn = w & 1;
  int l15 = lane & 15, quad = lane >> 4;

  f32x4 acc[4][4];
#pragma unroll
  for (int a = 0; a < 4; ++a)
#pragma unroll
    for (int b = 0; b < 4; ++b) acc[a][b] = (f32x4){0.f, 0.f, 0.f, 0.f};

  for (int kt = 0; kt < 256; kt += 64) {
    int kb = ks + kt;
    __syncthreads();
    stage_tile<128>(Ah, m0, kb, As_h, tid, NN);
    stage_tile<128>(Bh, 0, kb, Bs_h, tid, NN);
    if (TERMS == 3) {
      stage_tile<128>(Al, m0, kb, As_l, tid, NN);
      stage_tile<128>(Bl, 0, kb, Bs_l, tid, NN);
    }
    __syncthreads();
#pragma unroll
    for (int k0 = 0; k0 < 64; k0 += 32) {
      int ch = (k0 >> 3) + quad;
      short8 a_h[4], b_h[4], a_l[4], b_l[4];
#pragma unroll
      for (int f = 0; f < 4; ++f) {
        int ra = wm * 64 + f * 16 + l15;
        int cb = wn * 64 + f * 16 + l15;
        a_h[f] = frag(As_h, ra, ch);
        b_h[f] = frag(Bs_h, cb, ch);
        if (TERMS == 3) { a_l[f] = frag(As_l, ra, ch); b_l[f] = frag(Bs_l, cb, ch); }
      }
#pragma unroll
      for (int fm = 0; fm < 4; ++fm)
#pragma unroll
        for (int fn = 0; fn < 4; ++fn) {
          acc[fm][fn] = __builtin_amdgcn_mfma_f32_16x16x32_bf16(a_h[fm], b_h[fn], acc[fm][fn], 0, 0, 0);
          if (TERMS == 3) {
            acc[fm][fn] = __builtin_amdgcn_mfma_f32_16x16x32_bf16(a_h[fm], b_l[fn], acc[fm][fn], 0, 0, 0);
            acc[fm][fn] = __builtin_amdgcn_mfma_f32_16x16x32_bf16(a_l[fm], b_h[fn], acc[fm][fn], 0, 0, 0);
          }
        }
    }
  }
  float* Gp = G + (size_t)sp * NN * DD;
#pragma unroll
  for (int fm = 0; fm < 4; ++fm) {
    int rb = m0 + wm * 64 + fm * 16 + quad * 4;
#pragma unroll
    for (int fn = 0; fn < 4; ++fn) {
      int c = wn * 64 + fn * 16 + l15;
#pragma unroll
      for (int i = 0; i < 4; ++i)
        Gp[(size_t)(rb + i) * DD + c] = acc[fm][fn][i];
    }
  }
}

// ---------------- old fp32 GEMM (fallback tier only) ----------------
__global__ __launch_bounds__(256) void k_gemm_av(
    const float* __restrict__ A, const float* __restrict__ V,
    float* __restrict__ G, int ksplit) {
  int bx = blockIdx.x;
  int mt = bx & 63;
  int sp = bx >> 6;
  int m0 = mt * 64;
  int klen = NN / ksplit;
  int k0 = sp * klen;
  int tid = threadIdx.x;
  int tr = tid >> 4, tc = tid & 15;
  __shared__ float As[64 * 68];
  __shared__ float Bs[64 * 128];
  float acc[4][8];
#pragma unroll
  for (int r = 0; r < 4; ++r)
#pragma unroll
    for (int c = 0; c < 8; ++c) acc[r][c] = 0.f;
  for (int kt = 0; kt < klen; kt += 64) {
    int kb = k0 + kt;
    __syncthreads();
#pragma unroll
    for (int l = 0; l < 4; ++l) {
      int idx = tid + l * 256;
      int r = idx >> 4;
      int kq = (idx & 15) << 2;
      float4 a = *(const float4*)(A + (size_t)(m0 + r) * NN + kb + kq);
      As[(kq + 0) * 68 + r] = a.x;
      As[(kq + 1) * 68 + r] = a.y;
      As[(kq + 2) * 68 + r] = a.z;
      As[(kq + 3) * 68 + r] = a.w;
    }
#pragma unroll
    for (int l = 0; l < 8; ++l) {
      int idx = tid + l * 256;
      int kr = idx >> 5;
      int c4 = (idx & 31) << 2;
      *(float4*)(Bs + kr * 128 + c4) = *(const float4*)(V + (size_t)(kb + kr) * DD + c4);
    }
    __syncthreads();
#pragma unroll 8
    for (int kk = 0; kk < 64; ++kk) {
      float4 a = *(const float4*)(As + kk * 68 + tr * 4);
      float4 b0 = *(const float4*)(Bs + kk * 128 + tc * 8);
      float4 b1 = *(const float4*)(Bs + kk * 128 + tc * 8 + 4);
      float av[4] = {a.x, a.y, a.z, a.w};
      float bv[8] = {b0.x, b0.y, b0.z, b0.w, b1.x, b1.y, b1.z, b1.w};
#pragma unroll
      for (int r = 0; r < 4; ++r)
#pragma unroll
        for (int c = 0; c < 8; ++c) acc[r][c] = fmaf(av[r], bv[c], acc[r][c]);
    }
  }
  float* Gp = G + (size_t)sp * NN * DD;
#pragma unroll
  for (int r = 0; r < 4; ++r) {
    int gr = m0 + tr * 4 + r;
    float4 o0 = {acc[r][0], acc[r][1], acc[r][2], acc[r][3]};
    float4 o1 = {acc[r][4], acc[r][5], acc[r][6], acc[r][7]};
    *(float4*)(Gp + (size_t)gr * DD + tc * 8) = o0;
    *(float4*)(Gp + (size_t)gr * DD + tc * 8 + 4) = o1;
  }
}

// ---- K4/K7: Out = act( d * (sum_p G_p [+ sparse]) @ W + b ); optional sq + bf16 split ----
__global__ __launch_bounds__(256) void k_lin(
    const float* __restrict__ G, int nparts,
    const float* __restrict__ W, const float* __restrict__ bvec,
    const float* __restrict__ dvec, float* __restrict__ Out,
    int leaky, float* __restrict__ sqout,
    unsigned short* __restrict__ zh, unsigned short* __restrict__ zl,
    const float* __restrict__ Vsp, const float* __restrict__ sval,
    const int* __restrict__ sidx, const void* kptr) {
  int bx = blockIdx.x;
  int r0 = bx * 16;
  int tid = threadIdx.x;
  int tr = tid >> 4, tc = tid & 15;
  __shared__ float Gs[16 * 132];
  __shared__ float Ws[32 * 128];
  __shared__ float red[256];
  __shared__ float ds[16];

#pragma unroll
  for (int l = 0; l < 8; ++l) {
    int idx = tid + l * 256;
    int r = idx >> 7;
    int c = idx & 127;
    float v = 0.f;
    for (int p = 0; p < nparts; ++p)
      v += G[(size_t)p * NN * DD + (size_t)(r0 + r) * DD + c];
    Gs[r * 132 + c] = v;
  }
  if (tid < 16) ds[tid] = dvec[r0 + tid];

  if (sidx != nullptr) {
    __syncthreads();
    int kk = dec_i(kptr); kk = kk < 1 ? 1 : (kk > 8 ? 8 : kk);
    int gr = r0 + tr;
    float add[8] = {0, 0, 0, 0, 0, 0, 0, 0};
    for (int t = 0; t < kk; ++t) {
      float sv = sval[gr * 8 + t];
      int id = sidx[gr * 8 + t];
      const float4* vr = (const float4*)(Vsp + (size_t)id * DD);
      float4 w0 = vr[tc * 2], w1 = vr[tc * 2 + 1];
      add[0] = fmaf(sv, w0.x, add[0]); add[1] = fmaf(sv, w0.y, add[1]);
      add[2] = fmaf(sv, w0.z, add[2]); add[3] = fmaf(sv, w0.w, add[3]);
      add[4] = fmaf(sv, w1.x, add[4]); add[5] = fmaf(sv, w1.y, add[5]);
      add[6] = fmaf(sv, w1.z, add[6]); add[7] = fmaf(sv, w1.w, add[7]);
    }
#pragma unroll
    for (int u = 0; u < 8; ++u) Gs[tr * 132 + tc * 8 + u] += add[u];
  }

  float acc[8];
#pragma unroll
  for (int u = 0; u < 8; ++u) acc[u] = 0.f;

  for (int t0 = 0; t0 < 128; t0 += 32) {
    __syncthreads();
#pragma unroll
    for (int l = 0; l < 4; ++l) {
      int idx = tid + l * 256;
      int tt = idx >> 5;
      int c4 = (idx & 31) << 2;
      *(float4*)(Ws + tt * 128 + c4) = *(const float4*)(W + (size_t)(t0 + tt) * DD + c4);
    }
    __syncthreads();
#pragma unroll 8
    for (int tt = 0; tt < 32; ++tt) {
      float g = Gs[tr * 132 + t0 + tt];
      float4 w0 = *(const float4*)(Ws + tt * 128 + tc * 8);
      float4 w1 = *(const float4*)(Ws + tt * 128 + tc * 8 + 4);
      acc[0] = fmaf(g, w0.x, acc[0]); acc[1] = fmaf(g, w0.y, acc[1]);
      acc[2] = fmaf(g, w0.z, acc[2]); acc[3] = fmaf(g, w0.w, acc[3]);
      acc[4] = fmaf(g, w1.x, acc[4]); acc[5] = fmaf(g, w1.y, acc[5]);
      acc[6] = fmaf(g, w1.z, acc[6]); acc[7] = fmaf(g, w1.w, acc[7]);
    }
  }

  float d = ds[tr];
  float4 b0 = *(const float4*)(bvec + tc * 8);
  float4 b1 = *(const float4*)(bvec + tc * 8 + 4);
  float bb[8] = {b0.x, b0.y, b0.z, b0.w, b1.x, b1.y, b1.z, b1.w};
  float o[8];
#pragma unroll
  for (int u = 0; u < 8; ++u) {
    float v = fmaf(d, acc[u], bb[u]);
    if (leaky) v = v > 0.f ? v : 0.1f * v;
    o[u] = v;
  }
  size_t rowoff = (size_t)(r0 + tr) * DD + tc * 8;
  if (Out) {
    float4 o0 = {o[0], o[1], o[2], o[3]};
    float4 o1 = {o[4], o[5], o[6], o[7]};
    *(float4*)(Out + rowoff) = o0;
    *(float4*)(Out + rowoff + 4) = o1;
  }
  if (zh) {
    unsigned short hb[8], lb[8];
#pragma unroll
    for (int u = 0; u < 8; ++u) {
      hb[u] = f2bf(o[u]);
      lb[u] = f2bf(o[u] - bf2f(hb[u]));
    }
    ushort4 h0 = {hb[0], hb[1], hb[2], hb[3]};
    ushort4 h1 = {hb[4], hb[5], hb[6], hb[7]};
    ushort4 l0 = {lb[0], lb[1], lb[2], lb[3]};
    ushort4 l1 = {lb[4], lb[5], lb[6], lb[7]};
    *(ushort4*)(zh + rowoff) = h0;
    *(ushort4*)(zh + rowoff + 4) = h1;
    *(ushort4*)(zl + rowoff) = l0;
    *(ushort4*)(zl + rowoff + 4) = l1;
  }

  if (sqout != nullptr) {
    float p = 0.f;
#pragma unroll
    for (int u = 0; u < 8; ++u) p = fmaf(o[u], o[u], p);
    red[tid] = p;
    __syncthreads();
    if (tc == 0) {
      float s = 0.f;
#pragma unroll
      for (int i = 0; i < 16; ++i) s += red[tr * 16 + i];
      sqout[r0 + tr] = s;
    }
  }
}

// ---- K5: MFMA split-bf16 Z@Z^T, fused d2 + per-row partial top-8 ----
// grid 1024: mt = bx>>4 (64 m-tiles of 64), jp = bx&15 (16 j-slices of 256)
// block 256 thr, 4 waves 2x2; wave tile 32m x 64n; 2 j-tiles of 128
__global__ __launch_bounds__(256) void k_scores(
    const unsigned short* __restrict__ Zh, const unsigned short* __restrict__ Zl,
    const float* __restrict__ sq,
    float* __restrict__ pval, int* __restrict__ pidx, const void* sigptr) {
  __shared__ __align__(16) unsigned short Am[2][64 * 64];   // 16 KB; aliased by merge buf
  __shared__ __align__(16) unsigned short Bj[2][128 * 64];  // 32 KB; aliased by Stile
  __shared__ float sqj_s[256];
  __shared__ float sqi_s[64];
  float* Stile = (float*)&Bj[0][0];
  float* mv = (float*)&Am[0][0];
  int* mj = (int*)&Am[1][0];

  int bx = blockIdx.x;
  int mt = bx >> 4, jp = bx & 15;
  int m0 = mt * 64, j0 = jp * 256;
  int tid = threadIdx.x, lane = tid & 63, w = tid >> 6;
  int wm = w >> 1, wn = w & 1;
  int l15 = lane & 15, quad = lane >> 4;
  float inv2s = 0.5f / dec_f(sigptr);

  if (tid < 64) sqi_s[tid] = sq[m0 + tid];
  sqj_s[tid] = sq[j0 + tid];

  int sr = tid & 63;   // scan row
  int cg = tid >> 6;   // scan col-group

  float lv[8]; int lj[8];
#pragma unroll
  for (int s = 0; s < 8; ++s) { lv[s] = 3.4e38f; lj[s] = 0x7fffffff; }

  for (int jt = 0; jt < 2; ++jt) {
    int jrow0 = j0 + jt * 128;
    f32x4 acc[2][4];
#pragma unroll
    for (int a = 0; a < 2; ++a)
#pragma unroll
      for (int b = 0; b < 4; ++b) acc[a][b] = (f32x4){0.f, 0.f, 0.f, 0.f};

    for (int kh = 0; kh < 2; ++kh) {
      int kb = kh * 64;
      __syncthreads();  // prev Stile scan / frag reads done before restage
      stage_tile<64>(Zh, m0, kb, Am[0], tid, DD);
      stage_tile<64>(Zl, m0, kb, Am[1], tid, DD);
      stage_tile<128>(Zh, jrow0, kb, Bj[0], tid, DD);
      stage_tile<128>(Zl, jrow0, kb, Bj[1], tid, DD);
      __syncthreads();
#pragma unroll
      for (int k0 = 0; k0 < 64; k0 += 32) {
        int ch = (k0 >> 3) + quad;
        short8 ah[2], al[2], bh[4], bl[4];
#pragma unroll
        for (int f = 0; f < 2; ++f) {
          int ra = wm * 32 + f * 16 + l15;
          ah[f] = frag(Am[0], ra, ch);
          al[f] = frag(Am[1], ra, ch);
        }
#pragma unroll
        for (int f = 0; f < 4; ++f) {
          int cb = wn * 64 + f * 16 + l15;
          bh[f] = frag(Bj[0], cb, ch);
          bl[f] = frag(Bj[1], cb, ch);
        }
#pragma unroll
        for (int fm = 0; fm < 2; ++fm)
#pragma unroll
          for (int fn = 0; fn < 4; ++fn) {
            acc[fm][fn] = __builtin_amdgcn_mfma_f32_16x16x32_bf16(ah[fm], bh[fn], acc[fm][fn], 0, 0, 0);
            acc[fm][fn] = __builtin_amdgcn_mfma_f32_16x16x32_bf16(ah[fm], bl[fn], acc[fm][fn], 0, 0, 0);
            acc[fm][fn] = __builtin_amdgcn_mfma_f32_16x16x32_bf16(al[fm], bh[fn], acc[fm][fn], 0, 0, 0);
          }
      }
    }
    // epilogue: Stile[c][r] = sqj - 2*dot (Stile aliases Bj; MFMA reads are done)
    __syncthreads();
#pragma unroll
    for (int fm = 0; fm < 2; ++fm) {
      int rb = wm * 32 + fm * 16 + quad * 4;
#pragma unroll
      for (int fn = 0; fn < 4; ++fn) {
        int c = wn * 64 + fn * 16 + l15;
        float sqjv = sqj_s[jt * 128 + c];
        f32x4 a = acc[fm][fn];
        float4 vv = {fmaf(-2.f, a[0], sqjv), fmaf(-2.f, a[1], sqjv),
                     fmaf(-2.f, a[2], sqjv), fmaf(-2.f, a[3], sqjv)};
        *(float4*)(Stile + c * 64 + (rb ^ ((c & 7) << 3))) = vv;
      }
    }
    __syncthreads();
    float sqi_v = sqi_s[sr];
#pragma unroll 4
    for (int cc = 0; cc < 32; ++cc) {
      int c = cg * 32 + cc;
      float t = Stile[c * 64 + (sr ^ ((c & 7) << 3))];
      float d2 = fmaxf(sqi_v + t, 0.f);
      int jg = jrow0 + c;
      if (d2 < lv[7] || (d2 == lv[7] && jg < lj[7])) ins_asc<8>(lv, lj, d2, jg);
    }
  }

  // merge the 4 col-groups per row (LDS buffer aliases Am), convert kept d2 -> S
  __syncthreads();
#pragma unroll
  for (int s = 0; s < 8; ++s) {
    mv[(sr * 4 + cg) * 8 + s] = lv[s];
    mj[(sr * 4 + cg) * 8 + s] = lj[s];
  }
  __syncthreads();
  if (tid < 64) {
    float fv[8]; int fj[8];
#pragma unroll
    for (int s = 0; s < 8; ++s) { fv[s] = 3.4e38f; fj[s] = 0x7fffffff; }
    for (int g = 0; g < 4; ++g)
#pragma unroll
      for (int s = 0; s < 8; ++s) {
        float v = mv[(tid * 4 + g) * 8 + s];
        int j = mj[(tid * 4 + g) * 8 + s];
        if (v < fv[7] || (v == fv[7] && j < fj[7])) ins_asc<8>(fv, fj, v, j);
      }
    int grow = m0 + tid;
#pragma unroll
    for (int s = 0; s < 8; ++s) {
      pval[((size_t)grow * 16 + jp) * 8 + s] = __expf(-sqrtf(fv[s] + 1e-10f) * inv2s);
      pidx[((size_t)grow * 16 + jp) * 8 + s] = fj[s];
    }
  }
}

// ---- K5b: merge 16 partial lists, d2 = rsqrt(rowsumA + sum S), V = d2*x ----
__global__ __launch_bounds__(256) void k_merge(
    const float* __restrict__ pval, const int* __restrict__ pidx,
    const float* __restrict__ rowsumA, const float* __restrict__ x,
    float* __restrict__ sval, int* __restrict__ sidx,
    float* __restrict__ d2vec, float* __restrict__ V, const void* kptr) {
  int bx = blockIdx.x;
  int r0 = bx * 16;
  int tid = threadIdx.x;
  int kk = dec_i(kptr); kk = kk < 1 ? 1 : (kk > 8 ? 8 : kk);
  __shared__ float ds[16];
  if (tid < 16) {
    int r = r0 + tid;
    float fv[8]; int fj[8];
#pragma unroll
    for (int s = 0; s < 8; ++s) { fv[s] = -1.f; fj[s] = 0x7fffffff; }
    for (int p = 0; p < 16; ++p) {
#pragma unroll
      for (int s = 0; s < 8; ++s) {
        float v = pval[((size_t)r * 16 + p) * 8 + s];
        int j = pidx[((size_t)r * 16 + p) * 8 + s];
        if (v > fv[7] || (v == fv[7] && j < fj[7])) ins_desc<8>(fv, fj, v, j);
      }
    }
    float srow = 0.f;
#pragma unroll
    for (int s = 0; s < 8; ++s) if (s < kk) srow += fv[s];
    float dd = rsqrtf(rowsumA[r] + srow);
    d2vec[r] = dd;
    ds[tid] = dd;
#pragma unroll
    for (int s = 0; s < 8; ++s) if (s < kk) { sval[r * 8 + s] = fv[s]; sidx[r * 8 + s] = fj[s]; }
  }
  __syncthreads();
#pragma unroll
  for (int l = 0; l < 2; ++l) {
    int idx = tid + l * 256;
    int rl = idx >> 5;
    int c4 = (idx & 31) << 2;
    float4 xv = *(const float4*)(x + (size_t)(r0 + rl) * DD + c4);
    float dd = ds[rl];
    float4 o; o.x = dd * xv.x; o.y = dd * xv.y; o.z = dd * xv.z; o.w = dd * xv.w;
    *(float4*)(V + (size_t)(r0 + rl) * DD + c4) = o;
  }
}

extern "C" void kernel_launch(void* const* d_in, const int* in_sizes, int n_in,
                              void* d_out, int out_size, void* d_ws, size_t ws_size,
                              hipStream_t stream) {
  const float* x  = (const float*)d_in[0];
  const float* A  = (const float*)d_in[1];
  const float* W1 = (const float*)d_in[2];
  const float* b1 = (const float*)d_in[3];
  const float* W2 = (const float*)d_in[4];
  const float* b2 = (const float*)d_in[5];
  const void* sig = (n_in > 6) ? d_in[6] : nullptr;
  const void* kp  = (n_in > 7) ? d_in[7] : nullptr;

  float* ws = (float*)d_ws;
  float* rowsumA = ws;                               // 4096
  float* dvec    = ws + 4096;                        // 4096
  float* d2vec   = ws + 8192;                        // 4096
  float* sqv     = ws + 12288;                       // 4096
  float* sval    = ws + 16384;                       // 32768
  int*   sidx    = (int*)(ws + 49152);               // 32768
  float* pval    = ws + 81920;                       // 4096*16*8 = 524288
  int*   pidx    = (int*)(ws + 606208);              // 524288
  unsigned short* Zh = (unsigned short*)(ws + 1130496);  // 262144 floats
  unsigned short* Zl = (unsigned short*)(ws + 1392640);  // 262144 floats
  float* V       = ws + 1654784;                     // 524288

  const size_t F_FULL = 27869184;  // ~111.5 MB
  const size_t F_MID  = 19218432;  // ~76.9 MB
  int tier = (ws_size >= F_FULL * 4) ? 2 : (ws_size >= F_MID * 4) ? 1 : 0;

  if (tier >= 1) {
    unsigned short* VTh = (unsigned short*)(ws + 2179072);   // 262144 floats
    unsigned short* VTl;
    unsigned short* Ah;
    unsigned short* Al = nullptr;
    float* G;
    if (tier == 2) {
      VTl = (unsigned short*)(ws + 2441216);
      Ah  = (unsigned short*)(ws + 2703360);   // 8388608 floats
      Al  = (unsigned short*)(ws + 11091968);  // 8388608 floats
      G   = ws + 19480576;                     // 16*524288
    } else {
      VTl = nullptr;
      Ah  = (unsigned short*)(ws + 2441216);
      G   = ws + 10829824;
    }

    k_rowsum_scale<<<4096, 256, 0, stream>>>(A, x, rowsumA, dvec, V, Ah, Al);
    k_vt<<<64, 256, 0, stream>>>(V, VTh, VTl, tier == 2 ? 1 : 0);
    if (tier == 2)
      k_gemm_bf16<3><<<512, 256, 0, stream>>>(Ah, Al, VTh, VTl, G);
    else
      k_gemm_bf16<1><<<512, 256, 0, stream>>>(Ah, nullptr, VTh, nullptr, G);
    k_lin<<<256, 256, 0, stream>>>(G, 16, W1, b1, dvec, nullptr, 1, sqv, Zh, Zl,
                                   nullptr, nullptr, nullptr, nullptr);
    k_scores<<<1024, 256, 0, stream>>>(Zh, Zl, sqv, pval, pidx, sig);
    k_merge<<<256, 256, 0, stream>>>(pval, pidx, rowsumA, x, sval, sidx, d2vec, V, kp);
    k_vt<<<64, 256, 0, stream>>>(V, VTh, nullptr, 0);
    k_gemm_bf16<1><<<512, 256, 0, stream>>>(Ah, nullptr, VTh, nullptr, G);
    k_lin<<<256, 256, 0, stream>>>(G, 16, W2, b2, d2vec, (float*)d_out, 0, nullptr,
                                   nullptr, nullptr, V, sval, sidx, kp);
  } else {
    // LOW tier: fp32 gemm fallback
    float* G = ws + 2179072;
    const size_t nd = (size_t)NN * DD;
    int ksplit = 4;
    if (ws_size < (2179072 + 4 * nd) * 4) ksplit = 2;
    if (ws_size < (2179072 + 2 * nd) * 4) ksplit = 1;

    k_rowsum_scale<<<4096, 256, 0, stream>>>(A, x, rowsumA, dvec, V, nullptr, nullptr);
    k_gemm_av<<<64 * ksplit, 256, 0, stream>>>(A, V, G, ksplit);
    k_lin<<<256, 256, 0, stream>>>(G, ksplit, W1, b1, dvec, nullptr, 1, sqv, Zh, Zl,
                                   nullptr, nullptr, nullptr, nullptr);
    k_scores<<<1024, 256, 0, stream>>>(Zh, Zl, sqv, pval, pidx, sig);
    k_merge<<<256, 256, 0, stream>>>(pval, pidx, rowsumA, x, sval, sidx, d2vec, V, kp);
    k_gemm_av<<<64 * ksplit, 256, 0, stream>>>(A, V, G, ksplit);
    k_lin<<<256, 256, 0, stream>>>(G, ksplit, W2, b2, d2vec, (float*)d_out, 0, nullptr,
                                   nullptr, nullptr, V, sval, sidx, kp);
  }
}

// Round 5
// 359.247 us; speedup vs baseline: 2.2002x; 1.1504x over previous
//
#include <hip/hip_runtime.h>
#include <cstdint>
#include <cstddef>

#define NN 4096
#define DD 128

using short8 = __attribute__((ext_vector_type(8))) short;
using f32x4  = __attribute__((ext_vector_type(4))) float;

typedef __attribute__((address_space(1))) void gvoid;
typedef __attribute__((address_space(3))) void lvoid;

__device__ __forceinline__ void async16(const void* g, void* l) {
  __builtin_amdgcn_global_load_lds((gvoid*)g, (lvoid*)l, 16, 0, 0);
}

__device__ __forceinline__ float dec_f(const void* p) {
  if (!p) return 1.0f;
  int b = *(const int*)p;
  return (b >= 0 && b < 1000000) ? (float)b : __int_as_float(b);
}
__device__ __forceinline__ int dec_i(const void* p) {
  if (!p) return 4;
  int b = *(const int*)p;
  return (b >= 0 && b < 1000000) ? b : (int)__int_as_float(b);
}

__device__ __forceinline__ unsigned short f2bf(float f) {
  union { float f; unsigned int u; } v; v.f = f;
  unsigned int u = v.u;
  unsigned int r = (u + 0x7fffu + ((u >> 16) & 1u)) >> 16;
  return (unsigned short)r;
}
__device__ __forceinline__ float bf2f(unsigned short h) {
  union { unsigned int u; float f; } v; v.u = ((unsigned int)h) << 16;
  return v.f;
}

// descending by (val desc, idx asc)
template <int CAP>
__device__ __forceinline__ void ins_desc(float (&lv)[CAP], int (&lj)[CAP], float v, int j) {
  float cv = v; int cj = j;
#pragma unroll
  for (int t = 0; t < CAP; ++t) {
    bool bt = (cv > lv[t]) || (cv == lv[t] && cj < lj[t]);
    float tv = lv[t]; int tj = lj[t];
    if (bt) { lv[t] = cv; lj[t] = cj; cv = tv; cj = tj; }
  }
}
// ascending by (key asc, idx asc)
template <int CAP>
__device__ __forceinline__ void ins_asc(float (&lv)[CAP], int (&lj)[CAP], float v, int j) {
  float cv = v; int cj = j;
#pragma unroll
  for (int t = 0; t < CAP; ++t) {
    bool bt = (cv < lv[t]) || (cv == lv[t] && cj < lj[t]);
    float tv = lv[t]; int tj = lj[t];
    if (bt) { lv[t] = cv; lj[t] = cj; cv = tv; cj = tj; }
  }
}

// stage ROWS x KC bf16 tile (chunks of 8 ushorts; physical chunk p holds logical p^(r&7))
template <int ROWS, int KC, int NTHR>
__device__ __forceinline__ void stage2(const unsigned short* src, int row0, int kb,
                                       unsigned short* dst, int tid, int stride) {
  const int CPR = KC / 8;
  const int ITER = (ROWS * CPR) / NTHR;
#pragma unroll
  for (int t = 0; t < ITER; ++t) {
    int id = tid + t * NTHR;
    int r = id / CPR;
    int p = id % CPR;
    int lc = p ^ (r & 7);
    const void* g = src + (size_t)(row0 + r) * stride + kb + lc * 8;
    async16(g, dst + (size_t)(id & ~63) * 8);
  }
}

template <int CPR>
__device__ __forceinline__ short8 fragN(const unsigned short* t, int row, int ch) {
  return *(const short8*)(t + (size_t)(row * CPR + (ch ^ (row & 7))) * 8);
}

// ---------------- K1: rowsum(A), d = rsqrt, V = d*x, A -> bf16 hi/lo ----------------
__global__ __launch_bounds__(256) void k_rowsum_scale(
    const float* __restrict__ A, const float* __restrict__ x,
    float* __restrict__ rowsumA, float* __restrict__ dvec, float* __restrict__ V,
    unsigned short* __restrict__ Ah, unsigned short* __restrict__ Al) {
  int row = blockIdx.x;
  int tid = threadIdx.x;
  const float4* Arow = (const float4*)(A + (size_t)row * NN);
  float s = 0.f;
#pragma unroll
  for (int l = 0; l < 4; ++l) {
    int idx = tid + l * 256;
    float4 v = Arow[idx];
    s += (v.x + v.y) + (v.z + v.w);
    if (Ah) {
      ushort4 h = {f2bf(v.x), f2bf(v.y), f2bf(v.z), f2bf(v.w)};
      *(ushort4*)(Ah + (size_t)row * NN + idx * 4) = h;
      if (Al) {
        ushort4 lo = {f2bf(v.x - bf2f(h.x)), f2bf(v.y - bf2f(h.y)),
                      f2bf(v.z - bf2f(h.z)), f2bf(v.w - bf2f(h.w))};
        *(ushort4*)(Al + (size_t)row * NN + idx * 4) = lo;
      }
    }
  }
  __shared__ float red[256];
  __shared__ float dsh;
  red[tid] = s;
  __syncthreads();
  if (tid < 64) {
    s = red[tid] + red[tid + 64] + red[tid + 128] + red[tid + 192];
#pragma unroll
    for (int off = 32; off > 0; off >>= 1) s += __shfl_down(s, off, 64);
    if (tid == 0) { rowsumA[row] = s; float d = rsqrtf(s); dvec[row] = d; dsh = d; }
  }
  __syncthreads();
  float d = dsh;
  if (tid < 32) {
    float4 xv = ((const float4*)(x + (size_t)row * DD))[tid];
    float4 o; o.x = d * xv.x; o.y = d * xv.y; o.z = d * xv.z; o.w = d * xv.w;
    ((float4*)(V + (size_t)row * DD))[tid] = o;
  }
}

// ---------------- K2: V [4096][128] fp32 -> VT [128][4096] bf16 hi(/lo) ----------------
__global__ __launch_bounds__(256) void k_vt(
    const float* __restrict__ V, unsigned short* __restrict__ VTh,
    unsigned short* __restrict__ VTl, int emit_lo) {
  __shared__ float Ls[64 * 132];
  int bx = blockIdx.x, tid = threadIdx.x;
  int r0 = bx * 64;
#pragma unroll
  for (int l = 0; l < 8; ++l) {
    int idx = tid + l * 256;
    int r = idx >> 5, c4 = (idx & 31) << 2;
    *(float4*)(Ls + r * 132 + c4) = *(const float4*)(V + (size_t)(r0 + r) * DD + c4);
  }
  __syncthreads();
  int c = tid >> 1, rh = tid & 1;
  unsigned short hb[32], lb[32];
#pragma unroll
  for (int i = 0; i < 32; ++i) {
    float v = Ls[(rh * 32 + i) * 132 + c];
    hb[i] = f2bf(v);
    lb[i] = f2bf(v - bf2f(hb[i]));
  }
  size_t base = (size_t)c * NN + r0 + rh * 32;
#pragma unroll
  for (int q = 0; q < 8; ++q) {
    ushort4 h = {hb[q * 4], hb[q * 4 + 1], hb[q * 4 + 2], hb[q * 4 + 3]};
    *(ushort4*)(VTh + base + q * 4) = h;
  }
  if (emit_lo) {
#pragma unroll
    for (int q = 0; q < 8; ++q) {
      ushort4 lo = {lb[q * 4], lb[q * 4 + 1], lb[q * 4 + 2], lb[q * 4 + 3]};
      *(ushort4*)(VTl + base + q * 4) = lo;
    }
  }
}

// ---------------- K3/K6: MFMA bf16 GEMM  G_part = A[128 rows][256 k] @ V ----------------
template <int TERMS>
__global__ __launch_bounds__(256) void k_gemm_bf16(
    const unsigned short* __restrict__ Ah, const unsigned short* __restrict__ Al,
    const unsigned short* __restrict__ Bh, const unsigned short* __restrict__ Bl,
    float* __restrict__ G) {
  __shared__ __align__(16) unsigned short As_h[128 * 64];
  __shared__ __align__(16) unsigned short Bs_h[128 * 64];
  __shared__ __align__(16) unsigned short As_l[TERMS == 3 ? 128 * 64 : 8];
  __shared__ __align__(16) unsigned short Bs_l[TERMS == 3 ? 128 * 64 : 8];

  int bx = blockIdx.x;
  int mt = bx >> 4, sp = bx & 15;
  int m0 = mt * 128;
  int ks = sp * 256;
  int tid = threadIdx.x, lane = tid & 63, w = tid >> 6;
  int wm = w >> 1, wn = w & 1;
  int l15 = lane & 15, quad = lane >> 4;

  f32x4 acc[4][4];
#pragma unroll
  for (int a = 0; a < 4; ++a)
#pragma unroll
    for (int b = 0; b < 4; ++b) acc[a][b] = (f32x4){0.f, 0.f, 0.f, 0.f};

  for (int kt = 0; kt < 256; kt += 64) {
    int kb = ks + kt;
    __syncthreads();
    stage2<128, 64, 256>(Ah, m0, kb, As_h, tid, NN);
    stage2<128, 64, 256>(Bh, 0, kb, Bs_h, tid, NN);
    if (TERMS == 3) {
      stage2<128, 64, 256>(Al, m0, kb, As_l, tid, NN);
      stage2<128, 64, 256>(Bl, 0, kb, Bs_l, tid, NN);
    }
    __syncthreads();
#pragma unroll
    for (int k0 = 0; k0 < 64; k0 += 32) {
      int ch = (k0 >> 3) + quad;
      short8 a_h[4], b_h[4], a_l[4], b_l[4];
#pragma unroll
      for (int f = 0; f < 4; ++f) {
        int ra = wm * 64 + f * 16 + l15;
        int cb = wn * 64 + f * 16 + l15;
        a_h[f] = fragN<8>(As_h, ra, ch);
        b_h[f] = fragN<8>(Bs_h, cb, ch);
        if (TERMS == 3) { a_l[f] = fragN<8>(As_l, ra, ch); b_l[f] = fragN<8>(Bs_l, cb, ch); }
      }
#pragma unroll
      for (int fm = 0; fm < 4; ++fm)
#pragma unroll
        for (int fn = 0; fn < 4; ++fn) {
          acc[fm][fn] = __builtin_amdgcn_mfma_f32_16x16x32_bf16(a_h[fm], b_h[fn], acc[fm][fn], 0, 0, 0);
          if (TERMS == 3) {
            acc[fm][fn] = __builtin_amdgcn_mfma_f32_16x16x32_bf16(a_h[fm], b_l[fn], acc[fm][fn], 0, 0, 0);
            acc[fm][fn] = __builtin_amdgcn_mfma_f32_16x16x32_bf16(a_l[fm], b_h[fn], acc[fm][fn], 0, 0, 0);
          }
        }
    }
  }
  float* Gp = G + (size_t)sp * NN * DD;
#pragma unroll
  for (int fm = 0; fm < 4; ++fm) {
    int rb = m0 + wm * 64 + fm * 16 + quad * 4;
#pragma unroll
    for (int fn = 0; fn < 4; ++fn) {
      int c = wn * 64 + fn * 16 + l15;
#pragma unroll
      for (int i = 0; i < 4; ++i)
        Gp[(size_t)(rb + i) * DD + c] = acc[fm][fn][i];
    }
  }
}

// ---------------- old fp32 GEMM (fallback tier only) ----------------
__global__ __launch_bounds__(256) void k_gemm_av(
    const float* __restrict__ A, const float* __restrict__ V,
    float* __restrict__ G, int ksplit) {
  int bx = blockIdx.x;
  int mt = bx & 63;
  int sp = bx >> 6;
  int m0 = mt * 64;
  int klen = NN / ksplit;
  int k0 = sp * klen;
  int tid = threadIdx.x;
  int tr = tid >> 4, tc = tid & 15;
  __shared__ float As[64 * 68];
  __shared__ float Bs[64 * 128];
  float acc[4][8];
#pragma unroll
  for (int r = 0; r < 4; ++r)
#pragma unroll
    for (int c = 0; c < 8; ++c) acc[r][c] = 0.f;
  for (int kt = 0; kt < klen; kt += 64) {
    int kb = k0 + kt;
    __syncthreads();
#pragma unroll
    for (int l = 0; l < 4; ++l) {
      int idx = tid + l * 256;
      int r = idx >> 4;
      int kq = (idx & 15) << 2;
      float4 a = *(const float4*)(A + (size_t)(m0 + r) * NN + kb + kq);
      As[(kq + 0) * 68 + r] = a.x;
      As[(kq + 1) * 68 + r] = a.y;
      As[(kq + 2) * 68 + r] = a.z;
      As[(kq + 3) * 68 + r] = a.w;
    }
#pragma unroll
    for (int l = 0; l < 8; ++l) {
      int idx = tid + l * 256;
      int kr = idx >> 5;
      int c4 = (idx & 31) << 2;
      *(float4*)(Bs + kr * 128 + c4) = *(const float4*)(V + (size_t)(kb + kr) * DD + c4);
    }
    __syncthreads();
#pragma unroll 8
    for (int kk = 0; kk < 64; ++kk) {
      float4 a = *(const float4*)(As + kk * 68 + tr * 4);
      float4 b0 = *(const float4*)(Bs + kk * 128 + tc * 8);
      float4 b1 = *(const float4*)(Bs + kk * 128 + tc * 8 + 4);
      float av[4] = {a.x, a.y, a.z, a.w};
      float bv[8] = {b0.x, b0.y, b0.z, b0.w, b1.x, b1.y, b1.z, b1.w};
#pragma unroll
      for (int r = 0; r < 4; ++r)
#pragma unroll
        for (int c = 0; c < 8; ++c) acc[r][c] = fmaf(av[r], bv[c], acc[r][c]);
    }
  }
  float* Gp = G + (size_t)sp * NN * DD;
#pragma unroll
  for (int r = 0; r < 4; ++r) {
    int gr = m0 + tr * 4 + r;
    float4 o0 = {acc[r][0], acc[r][1], acc[r][2], acc[r][3]};
    float4 o1 = {acc[r][4], acc[r][5], acc[r][6], acc[r][7]};
    *(float4*)(Gp + (size_t)gr * DD + tc * 8) = o0;
    *(float4*)(Gp + (size_t)gr * DD + tc * 8 + 4) = o1;
  }
}

// ---- K4/K7: Out = act( d * (sum_p G_p [+ sparse]) @ W + b ); optional sq + bf16 split ----
template <int NP>
__global__ __launch_bounds__(256) void k_lin(
    const float* __restrict__ G,
    const float* __restrict__ W, const float* __restrict__ bvec,
    const float* __restrict__ dvec, float* __restrict__ Out,
    int leaky, float* __restrict__ sqout,
    unsigned short* __restrict__ zh, unsigned short* __restrict__ zl,
    const float* __restrict__ Vsp, const float* __restrict__ sval,
    const int* __restrict__ sidx, const void* kptr) {
  int bx = blockIdx.x;
  int r0 = bx * 16;
  int tid = threadIdx.x;
  int tr = tid >> 4, tc = tid & 15;
  __shared__ float Gs[16 * 132];
  __shared__ float Ws[32 * 128];
  __shared__ float red[256];
  __shared__ float ds[16];

#pragma unroll
  for (int l = 0; l < 8; ++l) {
    int idx = tid + l * 256;
    int r = idx >> 7;
    int c = idx & 127;
    float v = 0.f;
#pragma unroll
    for (int p = 0; p < NP; ++p)
      v += G[(size_t)p * NN * DD + (size_t)(r0 + r) * DD + c];
    Gs[r * 132 + c] = v;
  }
  if (tid < 16) ds[tid] = dvec[r0 + tid];

  if (sidx != nullptr) {
    __syncthreads();
    int kk = dec_i(kptr); kk = kk < 1 ? 1 : (kk > 8 ? 8 : kk);
    int gr = r0 + tr;
    float add[8] = {0, 0, 0, 0, 0, 0, 0, 0};
    for (int t = 0; t < kk; ++t) {
      float sv = sval[gr * 8 + t];
      int id = sidx[gr * 8 + t];
      const float4* vr = (const float4*)(Vsp + (size_t)id * DD);
      float4 w0 = vr[tc * 2], w1 = vr[tc * 2 + 1];
      add[0] = fmaf(sv, w0.x, add[0]); add[1] = fmaf(sv, w0.y, add[1]);
      add[2] = fmaf(sv, w0.z, add[2]); add[3] = fmaf(sv, w0.w, add[3]);
      add[4] = fmaf(sv, w1.x, add[4]); add[5] = fmaf(sv, w1.y, add[5]);
      add[6] = fmaf(sv, w1.z, add[6]); add[7] = fmaf(sv, w1.w, add[7]);
    }
#pragma unroll
    for (int u = 0; u < 8; ++u) Gs[tr * 132 + tc * 8 + u] += add[u];
  }

  float acc[8];
#pragma unroll
  for (int u = 0; u < 8; ++u) acc[u] = 0.f;

  for (int t0 = 0; t0 < 128; t0 += 32) {
    __syncthreads();
#pragma unroll
    for (int l = 0; l < 4; ++l) {
      int idx = tid + l * 256;
      int tt = idx >> 5;
      int c4 = (idx & 31) << 2;
      *(float4*)(Ws + tt * 128 + c4) = *(const float4*)(W + (size_t)(t0 + tt) * DD + c4);
    }
    __syncthreads();
#pragma unroll 8
    for (int tt = 0; tt < 32; ++tt) {
      float g = Gs[tr * 132 + t0 + tt];
      float4 w0 = *(const float4*)(Ws + tt * 128 + tc * 8);
      float4 w1 = *(const float4*)(Ws + tt * 128 + tc * 8 + 4);
      acc[0] = fmaf(g, w0.x, acc[0]); acc[1] = fmaf(g, w0.y, acc[1]);
      acc[2] = fmaf(g, w0.z, acc[2]); acc[3] = fmaf(g, w0.w, acc[3]);
      acc[4] = fmaf(g, w1.x, acc[4]); acc[5] = fmaf(g, w1.y, acc[5]);
      acc[6] = fmaf(g, w1.z, acc[6]); acc[7] = fmaf(g, w1.w, acc[7]);
    }
  }

  float d = ds[tr];
  float4 b0 = *(const float4*)(bvec + tc * 8);
  float4 b1 = *(const float4*)(bvec + tc * 8 + 4);
  float bb[8] = {b0.x, b0.y, b0.z, b0.w, b1.x, b1.y, b1.z, b1.w};
  float o[8];
#pragma unroll
  for (int u = 0; u < 8; ++u) {
    float v = fmaf(d, acc[u], bb[u]);
    if (leaky) v = v > 0.f ? v : 0.1f * v;
    o[u] = v;
  }
  size_t rowoff = (size_t)(r0 + tr) * DD + tc * 8;
  if (Out) {
    float4 o0 = {o[0], o[1], o[2], o[3]};
    float4 o1 = {o[4], o[5], o[6], o[7]};
    *(float4*)(Out + rowoff) = o0;
    *(float4*)(Out + rowoff + 4) = o1;
  }
  if (zh) {
    unsigned short hb[8], lb[8];
#pragma unroll
    for (int u = 0; u < 8; ++u) {
      hb[u] = f2bf(o[u]);
      lb[u] = f2bf(o[u] - bf2f(hb[u]));
    }
    ushort4 h0 = {hb[0], hb[1], hb[2], hb[3]};
    ushort4 h1 = {hb[4], hb[5], hb[6], hb[7]};
    ushort4 l0 = {lb[0], lb[1], lb[2], lb[3]};
    ushort4 l1 = {lb[4], lb[5], lb[6], lb[7]};
    *(ushort4*)(zh + rowoff) = h0;
    *(ushort4*)(zh + rowoff + 4) = h1;
    *(ushort4*)(zl + rowoff) = l0;
    *(ushort4*)(zl + rowoff + 4) = l1;
  }

  if (sqout != nullptr) {
    float p = 0.f;
#pragma unroll
    for (int u = 0; u < 8; ++u) p = fmaf(o[u], o[u], p);
    red[tid] = p;
    __syncthreads();
    if (tc == 0) {
      float s = 0.f;
#pragma unroll
      for (int i = 0; i < 16; ++i) s += red[tr * 16 + i];
      sqout[r0 + tr] = s;
    }
  }
}

// ---- K5: MFMA split-bf16 Z@Z^T, fused d2 + per-row partial top-8 ----
// grid 1024: mt = bx>>4 (64 m-tiles of 64), jp = bx&15 (16 j-slices of 256)
// block 512 thr (8 waves, 2x4); wave tile 32m x 32n per jt-half; 2 j-tiles of 128
__global__ __launch_bounds__(512, 4) void k_scores(
    const unsigned short* __restrict__ Zh, const unsigned short* __restrict__ Zl,
    const float* __restrict__ sq,
    float* __restrict__ pval, int* __restrict__ pidx, const void* sigptr) {
  __shared__ __align__(16) unsigned short Am[2][64 * 128];   // 32 KB (h,l); merge lists alias
  __shared__ __align__(16) unsigned short Bj[2][128 * 64];   // 32 KB (h,l); Stile aliases BOTH
  __shared__ float sqj_s[256];
  __shared__ float sqi_s[64];
  float* Stile = (float*)&Bj[0][0];   // [64 rows][stride 128] = exactly 32 KB
  float* mv = (float*)&Am[0][0];      // [512][8]
  int* mj = (int*)&Am[1][0];          // [512][8]

  int bx = blockIdx.x;
  int mt = bx >> 4, jp = bx & 15;
  int m0 = mt * 64, j0 = jp * 256;
  int tid = threadIdx.x, lane = tid & 63, w = tid >> 6;
  int wm = w >> 2, wn = w & 3;
  int l15 = lane & 15, quad = lane >> 4;
  float inv2s = 0.5f / dec_f(sigptr);

  if (tid < 256) sqj_s[tid] = sq[j0 + tid];
  if (tid < 64) sqi_s[tid] = sq[m0 + tid];

  // stage A-tile once: 64 rows x full 128 k, h + l
  stage2<64, 128, 512>(Zh, m0, 0, Am[0], tid, DD);
  stage2<64, 128, 512>(Zl, m0, 0, Am[1], tid, DD);

  int srow = tid >> 3;          // scan row 0..63
  int scol0 = (tid & 7) * 16;   // scan col base within 128

  float lv[8]; int lj[8];
#pragma unroll
  for (int s = 0; s < 8; ++s) { lv[s] = 3.4e38f; lj[s] = 0x7fffffff; }

  for (int jt = 0; jt < 2; ++jt) {
    int jrow0 = j0 + jt * 128;
    f32x4 acc[2][2];
#pragma unroll
    for (int a = 0; a < 2; ++a)
#pragma unroll
      for (int b = 0; b < 2; ++b) acc[a][b] = (f32x4){0.f, 0.f, 0.f, 0.f};

    for (int kh = 0; kh < 2; ++kh) {
      __syncthreads();   // prev phase (A-stage wait / Stile scan / frag reads) done
      stage2<128, 64, 512>(Zh, jrow0, kh * 64, Bj[0], tid, DD);
      stage2<128, 64, 512>(Zl, jrow0, kh * 64, Bj[1], tid, DD);
      __syncthreads();
#pragma unroll
      for (int k0 = 0; k0 < 64; k0 += 32) {
        int chA = kh * 8 + (k0 >> 3) + quad;
        int chB = (k0 >> 3) + quad;
        short8 ah[2], al[2], bh[2], bl[2];
#pragma unroll
        for (int f = 0; f < 2; ++f) {
          int ra = wm * 32 + f * 16 + l15;
          ah[f] = fragN<16>(Am[0], ra, chA);
          al[f] = fragN<16>(Am[1], ra, chA);
          int cb = wn * 32 + f * 16 + l15;
          bh[f] = fragN<8>(Bj[0], cb, chB);
          bl[f] = fragN<8>(Bj[1], cb, chB);
        }
#pragma unroll
        for (int fm = 0; fm < 2; ++fm)
#pragma unroll
          for (int fn = 0; fn < 2; ++fn) {
            acc[fm][fn] = __builtin_amdgcn_mfma_f32_16x16x32_bf16(ah[fm], bh[fn], acc[fm][fn], 0, 0, 0);
            acc[fm][fn] = __builtin_amdgcn_mfma_f32_16x16x32_bf16(ah[fm], bl[fn], acc[fm][fn], 0, 0, 0);
            acc[fm][fn] = __builtin_amdgcn_mfma_f32_16x16x32_bf16(al[fm], bh[fn], acc[fm][fn], 0, 0, 0);
          }
      }
    }
    // epilogue: Stile[row][col] = sqj - 2*dot, row stride 128 (aliases ALL of Bj; frag reads done)
    __syncthreads();
#pragma unroll
    for (int fm = 0; fm < 2; ++fm) {
      int rb = wm * 32 + fm * 16 + quad * 4;
#pragma unroll
      for (int fn = 0; fn < 2; ++fn) {
        int c = wn * 32 + fn * 16 + l15;
        float sqjv = sqj_s[jt * 128 + c];
        f32x4 a = acc[fm][fn];
#pragma unroll
        for (int i = 0; i < 4; ++i)
          Stile[(rb + i) * 128 + c] = fmaf(-2.f, a[i], sqjv);
      }
    }
    __syncthreads();
    // scan: 8 threads/row, 16 cands each (4 x float4); clamped-d2 key (matches reference ties)
    float sqi_r = sqi_s[srow];
#pragma unroll
    for (int q = 0; q < 4; ++q) {
      float4 kv = *(const float4*)(Stile + srow * 128 + scol0 + q * 4);
      int jg = jrow0 + scol0 + q * 4;
      float ke[4] = {kv.x, kv.y, kv.z, kv.w};
#pragma unroll
      for (int e = 0; e < 4; ++e) {
        float v = fmaxf(sqi_r + ke[e], 0.f);
        int j = jg + e;
        if (v < lv[7] || (v == lv[7] && j < lj[7])) ins_asc<8>(lv, lj, v, j);
      }
    }
  }

  // write per-thread lists (alias Am; all Am frag reads complete)
#pragma unroll
  for (int s = 0; s < 8; ++s) { mv[tid * 8 + s] = lv[s]; mj[tid * 8 + s] = lj[s]; }
  __syncthreads();
  if (tid < 64) {
    float fv[8]; int fj[8];
#pragma unroll
    for (int s = 0; s < 8; ++s) { fv[s] = 3.4e38f; fj[s] = 0x7fffffff; }
    for (int g = 0; g < 8; ++g) {
      int src = tid * 8 + g;
#pragma unroll
      for (int s = 0; s < 8; ++s) {
        float v = mv[src * 8 + s];
        int j = mj[src * 8 + s];
        if (v < fv[7] || (v == fv[7] && j < fj[7])) ins_asc<8>(fv, fj, v, j);
      }
    }
    int grow = m0 + tid;
#pragma unroll
    for (int s = 0; s < 8; ++s) {
      pval[((size_t)grow * 16 + jp) * 8 + s] = __expf(-sqrtf(fv[s] + 1e-10f) * inv2s);
      pidx[((size_t)grow * 16 + jp) * 8 + s] = fj[s];
    }
  }
}

// ---- K5b: merge 16 partial lists, d2 = rsqrt(rowsumA + sum S), V = d2*x ----
__global__ __launch_bounds__(256) void k_merge(
    const float* __restrict__ pval, const int* __restrict__ pidx,
    const float* __restrict__ rowsumA, const float* __restrict__ x,
    float* __restrict__ sval, int* __restrict__ sidx,
    float* __restrict__ d2vec, float* __restrict__ V, const void* kptr) {
  int bx = blockIdx.x;
  int r0 = bx * 16;
  int tid = threadIdx.x;
  int kk = dec_i(kptr); kk = kk < 1 ? 1 : (kk > 8 ? 8 : kk);
  __shared__ float ds[16];
  if (tid < 16) {
    int r = r0 + tid;
    float fv[8]; int fj[8];
#pragma unroll
    for (int s = 0; s < 8; ++s) { fv[s] = -1.f; fj[s] = 0x7fffffff; }
    for (int p = 0; p < 16; ++p) {
#pragma unroll
      for (int s = 0; s < 8; ++s) {
        float v = pval[((size_t)r * 16 + p) * 8 + s];
        int j = pidx[((size_t)r * 16 + p) * 8 + s];
        if (v > fv[7] || (v == fv[7] && j < fj[7])) ins_desc<8>(fv, fj, v, j);
      }
    }
    float srow = 0.f;
#pragma unroll
    for (int s = 0; s < 8; ++s) if (s < kk) srow += fv[s];
    float dd = rsqrtf(rowsumA[r] + srow);
    d2vec[r] = dd;
    ds[tid] = dd;
#pragma unroll
    for (int s = 0; s < 8; ++s) if (s < kk) { sval[r * 8 + s] = fv[s]; sidx[r * 8 + s] = fj[s]; }
  }
  __syncthreads();
#pragma unroll
  for (int l = 0; l < 2; ++l) {
    int idx = tid + l * 256;
    int rl = idx >> 5;
    int c4 = (idx & 31) << 2;
    float4 xv = *(const float4*)(x + (size_t)(r0 + rl) * DD + c4);
    float dd = ds[rl];
    float4 o; o.x = dd * xv.x; o.y = dd * xv.y; o.z = dd * xv.z; o.w = dd * xv.w;
    *(float4*)(V + (size_t)(r0 + rl) * DD + c4) = o;
  }
}

extern "C" void kernel_launch(void* const* d_in, const int* in_sizes, int n_in,
                              void* d_out, int out_size, void* d_ws, size_t ws_size,
                              hipStream_t stream) {
  const float* x  = (const float*)d_in[0];
  const float* A  = (const float*)d_in[1];
  const float* W1 = (const float*)d_in[2];
  const float* b1 = (const float*)d_in[3];
  const float* W2 = (const float*)d_in[4];
  const float* b2 = (const float*)d_in[5];
  const void* sig = (n_in > 6) ? d_in[6] : nullptr;
  const void* kp  = (n_in > 7) ? d_in[7] : nullptr;

  float* ws = (float*)d_ws;
  float* rowsumA = ws;                               // 4096
  float* dvec    = ws + 4096;                        // 4096
  float* d2vec   = ws + 8192;                        // 4096
  float* sqv     = ws + 12288;                       // 4096
  float* sval    = ws + 16384;                       // 32768
  int*   sidx    = (int*)(ws + 49152);               // 32768
  float* pval    = ws + 81920;                       // 4096*16*8 = 524288
  int*   pidx    = (int*)(ws + 606208);              // 524288
  unsigned short* Zh = (unsigned short*)(ws + 1130496);  // 262144 floats
  unsigned short* Zl = (unsigned short*)(ws + 1392640);  // 262144 floats
  float* V       = ws + 1654784;                     // 524288

  const size_t F_FULL = 27869184;  // ~111.5 MB
  const size_t F_MID  = 19218432;  // ~76.9 MB
  int tier = (ws_size >= F_FULL * 4) ? 2 : (ws_size >= F_MID * 4) ? 1 : 0;

  if (tier >= 1) {
    unsigned short* VTh = (unsigned short*)(ws + 2179072);   // 262144 floats
    unsigned short* VTl;
    unsigned short* Ah;
    unsigned short* Al = nullptr;
    float* G;
    if (tier == 2) {
      VTl = (unsigned short*)(ws + 2441216);
      Ah  = (unsigned short*)(ws + 2703360);   // 8388608 floats
      Al  = (unsigned short*)(ws + 11091968);  // 8388608 floats
      G   = ws + 19480576;                     // 16*524288
    } else {
      VTl = nullptr;
      Ah  = (unsigned short*)(ws + 2441216);
      G   = ws + 10829824;
    }

    k_rowsum_scale<<<4096, 256, 0, stream>>>(A, x, rowsumA, dvec, V, Ah, Al);
    k_vt<<<64, 256, 0, stream>>>(V, VTh, VTl, tier == 2 ? 1 : 0);
    if (tier == 2)
      k_gemm_bf16<3><<<512, 256, 0, stream>>>(Ah, Al, VTh, VTl, G);
    else
      k_gemm_bf16<1><<<512, 256, 0, stream>>>(Ah, nullptr, VTh, nullptr, G);
    k_lin<16><<<256, 256, 0, stream>>>(G, W1, b1, dvec, nullptr, 1, sqv, Zh, Zl,
                                       nullptr, nullptr, nullptr, nullptr);
    k_scores<<<1024, 512, 0, stream>>>(Zh, Zl, sqv, pval, pidx, sig);
    k_merge<<<256, 256, 0, stream>>>(pval, pidx, rowsumA, x, sval, sidx, d2vec, V, kp);
    k_vt<<<64, 256, 0, stream>>>(V, VTh, nullptr, 0);
    k_gemm_bf16<1><<<512, 256, 0, stream>>>(Ah, nullptr, VTh, nullptr, G);
    k_lin<16><<<256, 256, 0, stream>>>(G, W2, b2, d2vec, (float*)d_out, 0, nullptr,
                                       nullptr, nullptr, V, sval, sidx, kp);
  } else {
    // LOW tier: fp32 gemm fallback
    float* G = ws + 2179072;
    const size_t nd = (size_t)NN * DD;
    int ksplit = 4;
    if (ws_size < (2179072 + 4 * nd) * 4) ksplit = 2;
    if (ws_size < (2179072 + 2 * nd) * 4) ksplit = 1;

    k_rowsum_scale<<<4096, 256, 0, stream>>>(A, x, rowsumA, dvec, V, nullptr, nullptr);
    k_gemm_av<<<64 * ksplit, 256, 0, stream>>>(A, V, G, ksplit);
    if (ksplit == 4)
      k_lin<4><<<256, 256, 0, stream>>>(G, W1, b1, dvec, nullptr, 1, sqv, Zh, Zl,
                                        nullptr, nullptr, nullptr, nullptr);
    else if (ksplit == 2)
      k_lin<2><<<256, 256, 0, stream>>>(G, W1, b1, dvec, nullptr, 1, sqv, Zh, Zl,
                                        nullptr, nullptr, nullptr, nullptr);
    else
      k_lin<1><<<256, 256, 0, stream>>>(G, W1, b1, dvec, nullptr, 1, sqv, Zh, Zl,
                                        nullptr, nullptr, nullptr, nullptr);
    k_scores<<<1024, 512, 0, stream>>>(Zh, Zl, sqv, pval, pidx, sig);
    k_merge<<<256, 256, 0, stream>>>(pval, pidx, rowsumA, x, sval, sidx, d2vec, V, kp);
    k_gemm_av<<<64 * ksplit, 256, 0, stream>>>(A, V, G, ksplit);
    if (ksplit == 4)
      k_lin<4><<<256, 256, 0, stream>>>(G, W2, b2, d2vec, (float*)d_out, 0, nullptr,
                                        nullptr, nullptr, V, sval, sidx, kp);
    else if (ksplit == 2)
      k_lin<2><<<256, 256, 0, stream>>>(G, W2, b2, d2vec, (float*)d_out, 0, nullptr,
                                        nullptr, nullptr, V, sval, sidx, kp);
    else
      k_lin<1><<<256, 256, 0, stream>>>(G, W2, b2, d2vec, (float*)d_out, 0, nullptr,
                                        nullptr, nullptr, V, sval, sidx, kp);
  }
}

// Round 6
// 233.036 us; speedup vs baseline: 3.3918x; 1.5416x over previous
//
#include <hip/hip_runtime.h>
#include <cstdint>
#include <cstddef>

#define NN 4096
#define DD 128

using short8 = __attribute__((ext_vector_type(8))) short;
using f32x4  = __attribute__((ext_vector_type(4))) float;
typedef unsigned long long u64;

typedef __attribute__((address_space(1))) void gvoid;
typedef __attribute__((address_space(3))) void lvoid;

__device__ __forceinline__ void async16(const void* g, void* l) {
  __builtin_amdgcn_global_load_lds((gvoid*)g, (lvoid*)l, 16, 0, 0);
}

__device__ __forceinline__ float dec_f(const void* p) {
  if (!p) return 1.0f;
  int b = *(const int*)p;
  return (b >= 0 && b < 1000000) ? (float)b : __int_as_float(b);
}
__device__ __forceinline__ int dec_i(const void* p) {
  if (!p) return 4;
  int b = *(const int*)p;
  return (b >= 0 && b < 1000000) ? b : (int)__int_as_float(b);
}

__device__ __forceinline__ unsigned short f2bf(float f) {
  union { float f; unsigned int u; } v; v.f = f;
  unsigned int u = v.u;
  unsigned int r = (u + 0x7fffu + ((u >> 16) & 1u)) >> 16;
  return (unsigned short)r;
}
__device__ __forceinline__ float bf2f(unsigned short h) {
  union { unsigned int u; float f; } v; v.u = ((unsigned int)h) << 16;
  return v.f;
}

// sorted-4 insert of packed key (d2_bits<<32 | idx), ascending
__device__ __forceinline__ void ins4(u64 (&l)[4], u64 k) {
#pragma unroll
  for (int t = 0; t < 4; ++t) {
    u64 old = l[t];
    bool bt = k < old;
    l[t] = bt ? k : old;
    k = bt ? old : k;
  }
}

// stage ROWS x KC bf16 tile (16B chunks; physical chunk p holds logical p^(r&7))
template <int ROWS, int KC, int NTHR>
__device__ __forceinline__ void stage2(const unsigned short* src, int row0, int kb,
                                       unsigned short* dst, int tid, int stride) {
  const int CPR = KC / 8;
  const int ITER = (ROWS * CPR) / NTHR;
#pragma unroll
  for (int t = 0; t < ITER; ++t) {
    int id = tid + t * NTHR;
    int r = id / CPR;
    int p = id % CPR;
    int lc = p ^ (r & 7);
    const void* g = src + (size_t)(row0 + r) * stride + kb + lc * 8;
    async16(g, dst + (size_t)(id & ~63) * 8);
  }
}

template <int CPR>
__device__ __forceinline__ short8 fragN(const unsigned short* t, int row, int ch) {
  return *(const short8*)(t + (size_t)(row * CPR + (ch ^ (row & 7))) * 8);
}

// ---------------- K1: rowsum(A), d = rsqrt, V = d*x, A -> bf16 hi/lo ----------------
__global__ __launch_bounds__(256) void k_rowsum_scale(
    const float* __restrict__ A, const float* __restrict__ x,
    float* __restrict__ rowsumA, float* __restrict__ dvec, float* __restrict__ V,
    unsigned short* __restrict__ Ah, unsigned short* __restrict__ Al) {
  int row = blockIdx.x;
  int tid = threadIdx.x;
  const float4* Arow = (const float4*)(A + (size_t)row * NN);
  float s = 0.f;
#pragma unroll
  for (int l = 0; l < 4; ++l) {
    int idx = tid + l * 256;
    float4 v = Arow[idx];
    s += (v.x + v.y) + (v.z + v.w);
    if (Ah) {
      ushort4 h = {f2bf(v.x), f2bf(v.y), f2bf(v.z), f2bf(v.w)};
      *(ushort4*)(Ah + (size_t)row * NN + idx * 4) = h;
      if (Al) {
        ushort4 lo = {f2bf(v.x - bf2f(h.x)), f2bf(v.y - bf2f(h.y)),
                      f2bf(v.z - bf2f(h.z)), f2bf(v.w - bf2f(h.w))};
        *(ushort4*)(Al + (size_t)row * NN + idx * 4) = lo;
      }
    }
  }
  __shared__ float red[256];
  __shared__ float dsh;
  red[tid] = s;
  __syncthreads();
  if (tid < 64) {
    s = red[tid] + red[tid + 64] + red[tid + 128] + red[tid + 192];
#pragma unroll
    for (int off = 32; off > 0; off >>= 1) s += __shfl_down(s, off, 64);
    if (tid == 0) { rowsumA[row] = s; float d = rsqrtf(s); dvec[row] = d; dsh = d; }
  }
  __syncthreads();
  float d = dsh;
  if (tid < 32) {
    float4 xv = ((const float4*)(x + (size_t)row * DD))[tid];
    float4 o; o.x = d * xv.x; o.y = d * xv.y; o.z = d * xv.z; o.w = d * xv.w;
    ((float4*)(V + (size_t)row * DD))[tid] = o;
  }
}

// ---------------- K2: V [4096][128] fp32 -> VT [128][4096] bf16 hi(/lo) ----------------
__global__ __launch_bounds__(256) void k_vt(
    const float* __restrict__ V, unsigned short* __restrict__ VTh,
    unsigned short* __restrict__ VTl, int emit_lo) {
  __shared__ float Ls[64 * 132];
  int bx = blockIdx.x, tid = threadIdx.x;
  int r0 = bx * 64;
#pragma unroll
  for (int l = 0; l < 8; ++l) {
    int idx = tid + l * 256;
    int r = idx >> 5, c4 = (idx & 31) << 2;
    *(float4*)(Ls + r * 132 + c4) = *(const float4*)(V + (size_t)(r0 + r) * DD + c4);
  }
  __syncthreads();
  int c = tid >> 1, rh = tid & 1;
  unsigned short hb[32], lb[32];
#pragma unroll
  for (int i = 0; i < 32; ++i) {
    float v = Ls[(rh * 32 + i) * 132 + c];
    hb[i] = f2bf(v);
    lb[i] = f2bf(v - bf2f(hb[i]));
  }
  size_t base = (size_t)c * NN + r0 + rh * 32;
#pragma unroll
  for (int q = 0; q < 8; ++q) {
    ushort4 h = {hb[q * 4], hb[q * 4 + 1], hb[q * 4 + 2], hb[q * 4 + 3]};
    *(ushort4*)(VTh + base + q * 4) = h;
  }
  if (emit_lo) {
#pragma unroll
    for (int q = 0; q < 8; ++q) {
      ushort4 lo = {lb[q * 4], lb[q * 4 + 1], lb[q * 4 + 2], lb[q * 4 + 3]};
      *(ushort4*)(VTl + base + q * 4) = lo;
    }
  }
}

// ---------------- K3/K6: MFMA bf16 GEMM  G_part = A[128 rows][256 k] @ V ----------------
template <int TERMS>
__global__ __launch_bounds__(256) void k_gemm_bf16(
    const unsigned short* __restrict__ Ah, const unsigned short* __restrict__ Al,
    const unsigned short* __restrict__ Bh, const unsigned short* __restrict__ Bl,
    float* __restrict__ G) {
  __shared__ __align__(16) unsigned short As_h[128 * 64];
  __shared__ __align__(16) unsigned short Bs_h[128 * 64];
  __shared__ __align__(16) unsigned short As_l[TERMS == 3 ? 128 * 64 : 8];
  __shared__ __align__(16) unsigned short Bs_l[TERMS == 3 ? 128 * 64 : 8];

  int bx = blockIdx.x;
  int mt = bx >> 4, sp = bx & 15;
  int m0 = mt * 128;
  int ks = sp * 256;
  int tid = threadIdx.x, lane = tid & 63, w = tid >> 6;
  int wm = w >> 1, wn = w & 1;
  int l15 = lane & 15, quad = lane >> 4;

  f32x4 acc[4][4];
#pragma unroll
  for (int a = 0; a < 4; ++a)
#pragma unroll
    for (int b = 0; b < 4; ++b) acc[a][b] = (f32x4){0.f, 0.f, 0.f, 0.f};

  for (int kt = 0; kt < 256; kt += 64) {
    int kb = ks + kt;
    __syncthreads();
    stage2<128, 64, 256>(Ah, m0, kb, As_h, tid, NN);
    stage2<128, 64, 256>(Bh, 0, kb, Bs_h, tid, NN);
    if (TERMS == 3) {
      stage2<128, 64, 256>(Al, m0, kb, As_l, tid, NN);
      stage2<128, 64, 256>(Bl, 0, kb, Bs_l, tid, NN);
    }
    __syncthreads();
#pragma unroll
    for (int k0 = 0; k0 < 64; k0 += 32) {
      int ch = (k0 >> 3) + quad;
      short8 a_h[4], b_h[4], a_l[4], b_l[4];
#pragma unroll
      for (int f = 0; f < 4; ++f) {
        int ra = wm * 64 + f * 16 + l15;
        int cb = wn * 64 + f * 16 + l15;
        a_h[f] = fragN<8>(As_h, ra, ch);
        b_h[f] = fragN<8>(Bs_h, cb, ch);
        if (TERMS == 3) { a_l[f] = fragN<8>(As_l, ra, ch); b_l[f] = fragN<8>(Bs_l, cb, ch); }
      }
#pragma unroll
      for (int fm = 0; fm < 4; ++fm)
#pragma unroll
        for (int fn = 0; fn < 4; ++fn) {
          acc[fm][fn] = __builtin_amdgcn_mfma_f32_16x16x32_bf16(a_h[fm], b_h[fn], acc[fm][fn], 0, 0, 0);
          if (TERMS == 3) {
            acc[fm][fn] = __builtin_amdgcn_mfma_f32_16x16x32_bf16(a_h[fm], b_l[fn], acc[fm][fn], 0, 0, 0);
            acc[fm][fn] = __builtin_amdgcn_mfma_f32_16x16x32_bf16(a_l[fm], b_h[fn], acc[fm][fn], 0, 0, 0);
          }
        }
    }
  }
  float* Gp = G + (size_t)sp * NN * DD;
#pragma unroll
  for (int fm = 0; fm < 4; ++fm) {
    int rb = m0 + wm * 64 + fm * 16 + quad * 4;
#pragma unroll
    for (int fn = 0; fn < 4; ++fn) {
      int c = wn * 64 + fn * 16 + l15;
#pragma unroll
      for (int i = 0; i < 4; ++i)
        Gp[(size_t)(rb + i) * DD + c] = acc[fm][fn][i];
    }
  }
}

// ---------------- old fp32 GEMM (fallback tier only) ----------------
__global__ __launch_bounds__(256) void k_gemm_av(
    const float* __restrict__ A, const float* __restrict__ V,
    float* __restrict__ G, int ksplit) {
  int bx = blockIdx.x;
  int mt = bx & 63;
  int sp = bx >> 6;
  int m0 = mt * 64;
  int klen = NN / ksplit;
  int k0 = sp * klen;
  int tid = threadIdx.x;
  int tr = tid >> 4, tc = tid & 15;
  __shared__ float As[64 * 68];
  __shared__ float Bs[64 * 128];
  float acc[4][8];
#pragma unroll
  for (int r = 0; r < 4; ++r)
#pragma unroll
    for (int c = 0; c < 8; ++c) acc[r][c] = 0.f;
  for (int kt = 0; kt < klen; kt += 64) {
    int kb = k0 + kt;
    __syncthreads();
#pragma unroll
    for (int l = 0; l < 4; ++l) {
      int idx = tid + l * 256;
      int r = idx >> 4;
      int kq = (idx & 15) << 2;
      float4 a = *(const float4*)(A + (size_t)(m0 + r) * NN + kb + kq);
      As[(kq + 0) * 68 + r] = a.x;
      As[(kq + 1) * 68 + r] = a.y;
      As[(kq + 2) * 68 + r] = a.z;
      As[(kq + 3) * 68 + r] = a.w;
    }
#pragma unroll
    for (int l = 0; l < 8; ++l) {
      int idx = tid + l * 256;
      int kr = idx >> 5;
      int c4 = (idx & 31) << 2;
      *(float4*)(Bs + kr * 128 + c4) = *(const float4*)(V + (size_t)(kb + kr) * DD + c4);
    }
    __syncthreads();
#pragma unroll 8
    for (int kk = 0; kk < 64; ++kk) {
      float4 a = *(const float4*)(As + kk * 68 + tr * 4);
      float4 b0 = *(const float4*)(Bs + kk * 128 + tc * 8);
      float4 b1 = *(const float4*)(Bs + kk * 128 + tc * 8 + 4);
      float av[4] = {a.x, a.y, a.z, a.w};
      float bv[8] = {b0.x, b0.y, b0.z, b0.w, b1.x, b1.y, b1.z, b1.w};
#pragma unroll
      for (int r = 0; r < 4; ++r)
#pragma unroll
        for (int c = 0; c < 8; ++c) acc[r][c] = fmaf(av[r], bv[c], acc[r][c]);
    }
  }
  float* Gp = G + (size_t)sp * NN * DD;
#pragma unroll
  for (int r = 0; r < 4; ++r) {
    int gr = m0 + tr * 4 + r;
    float4 o0 = {acc[r][0], acc[r][1], acc[r][2], acc[r][3]};
    float4 o1 = {acc[r][4], acc[r][5], acc[r][6], acc[r][7]};
    *(float4*)(Gp + (size_t)gr * DD + tc * 8) = o0;
    *(float4*)(Gp + (size_t)gr * DD + tc * 8 + 4) = o1;
  }
}

// ---- K4/K7: Out = act( d * (sum_p G_p [+ sparse]) @ W + b ); optional sq + bf16 split ----
template <int NP>
__global__ __launch_bounds__(256) void k_lin(
    const float* __restrict__ G,
    const float* __restrict__ W, const float* __restrict__ bvec,
    const float* __restrict__ dvec, float* __restrict__ Out,
    int leaky, float* __restrict__ sqout,
    unsigned short* __restrict__ zh, unsigned short* __restrict__ zl,
    const float* __restrict__ Vsp, const float* __restrict__ sval,
    const int* __restrict__ sidx, const void* kptr) {
  int bx = blockIdx.x;
  int r0 = bx * 16;
  int tid = threadIdx.x;
  int tr = tid >> 4, tc = tid & 15;
  __shared__ float Gs[16 * 132];
  __shared__ float Ws[32 * 128];
  __shared__ float red[256];
  __shared__ float ds[16];

#pragma unroll
  for (int l = 0; l < 8; ++l) {
    int idx = tid + l * 256;
    int r = idx >> 7;
    int c = idx & 127;
    float v = 0.f;
#pragma unroll
    for (int p = 0; p < NP; ++p)
      v += G[(size_t)p * NN * DD + (size_t)(r0 + r) * DD + c];
    Gs[r * 132 + c] = v;
  }
  if (tid < 16) ds[tid] = dvec[r0 + tid];

  if (sidx != nullptr) {
    __syncthreads();
    int kk = dec_i(kptr); kk = kk < 1 ? 1 : (kk > 4 ? 4 : kk);
    int gr = r0 + tr;
    float add[8] = {0, 0, 0, 0, 0, 0, 0, 0};
    for (int t = 0; t < kk; ++t) {
      float sv = sval[gr * 8 + t];
      int id = sidx[gr * 8 + t];
      const float4* vr = (const float4*)(Vsp + (size_t)id * DD);
      float4 w0 = vr[tc * 2], w1 = vr[tc * 2 + 1];
      add[0] = fmaf(sv, w0.x, add[0]); add[1] = fmaf(sv, w0.y, add[1]);
      add[2] = fmaf(sv, w0.z, add[2]); add[3] = fmaf(sv, w0.w, add[3]);
      add[4] = fmaf(sv, w1.x, add[4]); add[5] = fmaf(sv, w1.y, add[5]);
      add[6] = fmaf(sv, w1.z, add[6]); add[7] = fmaf(sv, w1.w, add[7]);
    }
#pragma unroll
    for (int u = 0; u < 8; ++u) Gs[tr * 132 + tc * 8 + u] += add[u];
  }

  float acc[8];
#pragma unroll
  for (int u = 0; u < 8; ++u) acc[u] = 0.f;

  for (int t0 = 0; t0 < 128; t0 += 32) {
    __syncthreads();
#pragma unroll
    for (int l = 0; l < 4; ++l) {
      int idx = tid + l * 256;
      int tt = idx >> 5;
      int c4 = (idx & 31) << 2;
      *(float4*)(Ws + tt * 128 + c4) = *(const float4*)(W + (size_t)(t0 + tt) * DD + c4);
    }
    __syncthreads();
#pragma unroll 8
    for (int tt = 0; tt < 32; ++tt) {
      float g = Gs[tr * 132 + t0 + tt];
      float4 w0 = *(const float4*)(Ws + tt * 128 + tc * 8);
      float4 w1 = *(const float4*)(Ws + tt * 128 + tc * 8 + 4);
      acc[0] = fmaf(g, w0.x, acc[0]); acc[1] = fmaf(g, w0.y, acc[1]);
      acc[2] = fmaf(g, w0.z, acc[2]); acc[3] = fmaf(g, w0.w, acc[3]);
      acc[4] = fmaf(g, w1.x, acc[4]); acc[5] = fmaf(g, w1.y, acc[5]);
      acc[6] = fmaf(g, w1.z, acc[6]); acc[7] = fmaf(g, w1.w, acc[7]);
    }
  }

  float d = ds[tr];
  float4 b0 = *(const float4*)(bvec + tc * 8);
  float4 b1 = *(const float4*)(bvec + tc * 8 + 4);
  float bb[8] = {b0.x, b0.y, b0.z, b0.w, b1.x, b1.y, b1.z, b1.w};
  float o[8];
#pragma unroll
  for (int u = 0; u < 8; ++u) {
    float v = fmaf(d, acc[u], bb[u]);
    if (leaky) v = v > 0.f ? v : 0.1f * v;
    o[u] = v;
  }
  size_t rowoff = (size_t)(r0 + tr) * DD + tc * 8;
  if (Out) {
    float4 o0 = {o[0], o[1], o[2], o[3]};
    float4 o1 = {o[4], o[5], o[6], o[7]};
    *(float4*)(Out + rowoff) = o0;
    *(float4*)(Out + rowoff + 4) = o1;
  }
  if (zh) {
    unsigned short hb[8], lb[8];
#pragma unroll
    for (int u = 0; u < 8; ++u) {
      hb[u] = f2bf(o[u]);
      lb[u] = f2bf(o[u] - bf2f(hb[u]));
    }
    ushort4 h0 = {hb[0], hb[1], hb[2], hb[3]};
    ushort4 h1 = {hb[4], hb[5], hb[6], hb[7]};
    ushort4 l0 = {lb[0], lb[1], lb[2], lb[3]};
    ushort4 l1 = {lb[4], lb[5], lb[6], lb[7]};
    *(ushort4*)(zh + rowoff) = h0;
    *(ushort4*)(zh + rowoff + 4) = h1;
    *(ushort4*)(zl + rowoff) = l0;
    *(ushort4*)(zl + rowoff + 4) = l1;
  }

  if (sqout != nullptr) {
    float p = 0.f;
#pragma unroll
    for (int u = 0; u < 8; ++u) p = fmaf(o[u], o[u], p);
    red[tid] = p;
    __syncthreads();
    if (tc == 0) {
      float s = 0.f;
#pragma unroll
      for (int i = 0; i < 16; ++i) s += red[tr * 16 + i];
      sqout[r0 + tr] = s;
    }
  }
}

// ---- K5: MFMA split-bf16 Z@Z^T, fused d2-key top-4 per (row, j-slice) ----
// grid 1024: mt = bx>>4 (64 m-tiles of 64), jp = bx&15 (16 j-slices of 256)
// block 512 (8 waves, 2x4); LDS exactly 64 KB: Am 32K (full-K A h+l) + Bj 32K (64-j full-K h+l)
__global__ __launch_bounds__(512) void k_scores(
    const unsigned short* __restrict__ Zh, const unsigned short* __restrict__ Zl,
    const float* __restrict__ sq, u64* __restrict__ pkey) {
  __shared__ __align__(16) unsigned short Am[2][64 * 128];   // 32 KB; merge lists alias
  __shared__ __align__(16) unsigned short Bj[2][64 * 128];   // 32 KB; Stile aliases Bj[0]
  float* Stile = (float*)&Bj[0][0];          // [64][64], XOR-swizzled float4 slots
  u64* mv = (u64*)&Am[0][0];                 // [512][4] packed keys (16 KB)

  int bx = blockIdx.x;
  int mt = bx >> 4, jp = bx & 15;
  int m0 = mt * 64, j0 = jp * 256;
  int tid = threadIdx.x, lane = tid & 63, w = tid >> 6;
  int wm = w >> 2, wn = w & 3;               // wave tile: 32 rows x 16 cols
  int l15 = lane & 15, quad = lane >> 4;

  // stage A-tile once: 64 rows x 128 k, hi + lo
  stage2<64, 128, 512>(Zh, m0, 0, Am[0], tid, DD);
  stage2<64, 128, 512>(Zl, m0, 0, Am[1], tid, DD);

  int srow = tid >> 3;         // scan row 0..63
  int sc = tid & 7;            // scan col-octet
  float sqi_r = sq[m0 + srow];

  u64 lst[4];
#pragma unroll
  for (int s = 0; s < 4; ++s) lst[s] = ~0ull;

  for (int jt = 0; jt < 4; ++jt) {
    int jrow0 = j0 + jt * 64;
    __syncthreads();           // prev scan done (Stile = Bj[0] about to be restaged)
    stage2<64, 128, 512>(Zh, jrow0, 0, Bj[0], tid, DD);
    stage2<64, 128, 512>(Zl, jrow0, 0, Bj[1], tid, DD);
    __syncthreads();           // DMA visible (covers A on first iter)

    f32x4 acc[2];
    acc[0] = (f32x4){0.f, 0.f, 0.f, 0.f};
    acc[1] = (f32x4){0.f, 0.f, 0.f, 0.f};
#pragma unroll
    for (int kc = 0; kc < 4; ++kc) {
      int ch = kc * 4 + quad;
      short8 ah0 = fragN<16>(Am[0], wm * 32 + l15, ch);
      short8 ah1 = fragN<16>(Am[0], wm * 32 + 16 + l15, ch);
      short8 al0 = fragN<16>(Am[1], wm * 32 + l15, ch);
      short8 al1 = fragN<16>(Am[1], wm * 32 + 16 + l15, ch);
      short8 bh  = fragN<16>(Bj[0], wn * 16 + l15, ch);
      short8 bl  = fragN<16>(Bj[1], wn * 16 + l15, ch);
      acc[0] = __builtin_amdgcn_mfma_f32_16x16x32_bf16(ah0, bh, acc[0], 0, 0, 0);
      acc[0] = __builtin_amdgcn_mfma_f32_16x16x32_bf16(ah0, bl, acc[0], 0, 0, 0);
      acc[0] = __builtin_amdgcn_mfma_f32_16x16x32_bf16(al0, bh, acc[0], 0, 0, 0);
      acc[1] = __builtin_amdgcn_mfma_f32_16x16x32_bf16(ah1, bh, acc[1], 0, 0, 0);
      acc[1] = __builtin_amdgcn_mfma_f32_16x16x32_bf16(ah1, bl, acc[1], 0, 0, 0);
      acc[1] = __builtin_amdgcn_mfma_f32_16x16x32_bf16(al1, bh, acc[1], 0, 0, 0);
    }
    __syncthreads();           // all Bj/Am frag reads done before Stile clobbers Bj[0]

    // epilogue: Stile[r][c] = sqj - 2*dot, swizzled slot = (c>>2)^(r&7)
    {
      int c = wn * 16 + l15;
      float sqjv = sq[jrow0 + c];
      int cslot = c >> 2, cw = c & 3;
#pragma unroll
      for (int fm = 0; fm < 2; ++fm) {
        int rb = wm * 32 + fm * 16 + quad * 4;
#pragma unroll
        for (int i = 0; i < 4; ++i) {
          int r = rb + i;
          Stile[r * 64 + ((cslot ^ (r & 7)) << 2) + cw] = fmaf(-2.f, acc[fm][i], sqjv);
        }
      }
    }
    __syncthreads();           // Stile visible

    // scan: 8 threads/row, 8 cands each (2 swizzled float4 reads, 8-way floor)
#pragma unroll
    for (int q = 0; q < 2; ++q) {
      int slot = sc * 2 + q;
      float4 kv = *(const float4*)(Stile + srow * 64 + ((slot ^ (srow & 7)) << 2));
      int jb = jrow0 + sc * 8 + q * 4;
      float ke[4] = {kv.x, kv.y, kv.z, kv.w};
#pragma unroll
      for (int e = 0; e < 4; ++e) {
        float v = fmaxf(sqi_r + ke[e], 0.f);
        ins4(lst, ((u64)__float_as_uint(v) << 32) | (unsigned)(jb + e));
      }
    }
  }

  __syncthreads();             // last scan + last Am frag reads done
#pragma unroll
  for (int s = 0; s < 4; ++s) mv[tid * 4 + s] = lst[s];
  __syncthreads();
  if (tid < 64) {
    u64 best[4] = {~0ull, ~0ull, ~0ull, ~0ull};
    for (int g = 0; g < 8; ++g) {
      int src = tid * 8 + g;
#pragma unroll
      for (int s = 0; s < 4; ++s) ins4(best, mv[src * 4 + s]);
    }
#pragma unroll
    for (int s = 0; s < 4; ++s)
      pkey[((size_t)(m0 + tid) * 16 + jp) * 4 + s] = best[s];
  }
}

// ---- K5b: merge 16 partial key-lists, compute S, d2 = rsqrt(rowsumA + sum S), V = d2*x ----
__global__ __launch_bounds__(256) void k_merge(
    const u64* __restrict__ pkey,
    const float* __restrict__ rowsumA, const float* __restrict__ x,
    float* __restrict__ sval, int* __restrict__ sidx,
    float* __restrict__ d2vec, float* __restrict__ V,
    const void* kptr, const void* sigptr) {
  int bx = blockIdx.x;
  int r0 = bx * 16;
  int tid = threadIdx.x;
  int kk = dec_i(kptr); kk = kk < 1 ? 1 : (kk > 4 ? 4 : kk);
  float inv2s = 0.5f / dec_f(sigptr);
  __shared__ float ds[16];
  if (tid < 16) {
    int r = r0 + tid;
    u64 best[4] = {~0ull, ~0ull, ~0ull, ~0ull};
    for (int p = 0; p < 16; ++p) {
#pragma unroll
      for (int s = 0; s < 4; ++s) ins4(best, pkey[((size_t)r * 16 + p) * 4 + s]);
    }
    float srw = 0.f;
#pragma unroll
    for (int s = 0; s < 4; ++s) {
      if (s < kk) {
        float d2 = __uint_as_float((unsigned)(best[s] >> 32));
        float S = __expf(-sqrtf(d2 + 1e-10f) * inv2s);
        sval[r * 8 + s] = S;
        sidx[r * 8 + s] = (int)(best[s] & 0xffffffffu);
        srw += S;
      }
    }
    float dd = rsqrtf(rowsumA[r] + srw);
    d2vec[r] = dd;
    ds[tid] = dd;
  }
  __syncthreads();
#pragma unroll
  for (int l = 0; l < 2; ++l) {
    int idx = tid + l * 256;
    int rl = idx >> 5;
    int c4 = (idx & 31) << 2;
    float4 xv = *(const float4*)(x + (size_t)(r0 + rl) * DD + c4);
    float dd = ds[rl];
    float4 o; o.x = dd * xv.x; o.y = dd * xv.y; o.z = dd * xv.z; o.w = dd * xv.w;
    *(float4*)(V + (size_t)(r0 + rl) * DD + c4) = o;
  }
}

extern "C" void kernel_launch(void* const* d_in, const int* in_sizes, int n_in,
                              void* d_out, int out_size, void* d_ws, size_t ws_size,
                              hipStream_t stream) {
  const float* x  = (const float*)d_in[0];
  const float* A  = (const float*)d_in[1];
  const float* W1 = (const float*)d_in[2];
  const float* b1 = (const float*)d_in[3];
  const float* W2 = (const float*)d_in[4];
  const float* b2 = (const float*)d_in[5];
  const void* sig = (n_in > 6) ? d_in[6] : nullptr;
  const void* kp  = (n_in > 7) ? d_in[7] : nullptr;

  float* ws = (float*)d_ws;
  float* rowsumA = ws;                               // 4096
  float* dvec    = ws + 4096;                        // 4096
  float* d2vec   = ws + 8192;                        // 4096
  float* sqv     = ws + 12288;                       // 4096
  float* sval    = ws + 16384;                       // 32768
  int*   sidx    = (int*)(ws + 49152);               // 32768
  u64*   pkey    = (u64*)(ws + 81920);               // 4096*16*4 u64 = 2 MB (524288 floats)
  unsigned short* Zh = (unsigned short*)(ws + 1130496);  // 262144 floats
  unsigned short* Zl = (unsigned short*)(ws + 1392640);  // 262144 floats
  float* V       = ws + 1654784;                     // 524288

  const size_t F_FULL = 27869184;  // ~111.5 MB
  const size_t F_MID  = 19218432;  // ~76.9 MB
  int tier = (ws_size >= F_FULL * 4) ? 2 : (ws_size >= F_MID * 4) ? 1 : 0;

  if (tier >= 1) {
    unsigned short* VTh = (unsigned short*)(ws + 2179072);   // 262144 floats
    unsigned short* VTl;
    unsigned short* Ah;
    unsigned short* Al = nullptr;
    float* G;
    if (tier == 2) {
      VTl = (unsigned short*)(ws + 2441216);
      Ah  = (unsigned short*)(ws + 2703360);   // 8388608 floats
      Al  = (unsigned short*)(ws + 11091968);  // 8388608 floats
      G   = ws + 19480576;                     // 16*524288
    } else {
      VTl = nullptr;
      Ah  = (unsigned short*)(ws + 2441216);
      G   = ws + 10829824;
    }

    k_rowsum_scale<<<4096, 256, 0, stream>>>(A, x, rowsumA, dvec, V, Ah, Al);
    k_vt<<<64, 256, 0, stream>>>(V, VTh, VTl, tier == 2 ? 1 : 0);
    if (tier == 2)
      k_gemm_bf16<3><<<512, 256, 0, stream>>>(Ah, Al, VTh, VTl, G);
    else
      k_gemm_bf16<1><<<512, 256, 0, stream>>>(Ah, nullptr, VTh, nullptr, G);
    k_lin<16><<<256, 256, 0, stream>>>(G, W1, b1, dvec, nullptr, 1, sqv, Zh, Zl,
                                       nullptr, nullptr, nullptr, nullptr);
    k_scores<<<1024, 512, 0, stream>>>(Zh, Zl, sqv, pkey);
    k_merge<<<256, 256, 0, stream>>>(pkey, rowsumA, x, sval, sidx, d2vec, V, kp, sig);
    k_vt<<<64, 256, 0, stream>>>(V, VTh, nullptr, 0);
    k_gemm_bf16<1><<<512, 256, 0, stream>>>(Ah, nullptr, VTh, nullptr, G);
    k_lin<16><<<256, 256, 0, stream>>>(G, W2, b2, d2vec, (float*)d_out, 0, nullptr,
                                       nullptr, nullptr, V, sval, sidx, kp);
  } else {
    // LOW tier: fp32 gemm fallback
    float* G = ws + 2179072;
    const size_t nd = (size_t)NN * DD;
    int ksplit = 4;
    if (ws_size < (2179072 + 4 * nd) * 4) ksplit = 2;
    if (ws_size < (2179072 + 2 * nd) * 4) ksplit = 1;

    k_rowsum_scale<<<4096, 256, 0, stream>>>(A, x, rowsumA, dvec, V, nullptr, nullptr);
    k_gemm_av<<<64 * ksplit, 256, 0, stream>>>(A, V, G, ksplit);
    if (ksplit == 4)
      k_lin<4><<<256, 256, 0, stream>>>(G, W1, b1, dvec, nullptr, 1, sqv, Zh, Zl,
                                        nullptr, nullptr, nullptr, nullptr);
    else if (ksplit == 2)
      k_lin<2><<<256, 256, 0, stream>>>(G, W1, b1, dvec, nullptr, 1, sqv, Zh, Zl,
                                        nullptr, nullptr, nullptr, nullptr);
    else
      k_lin<1><<<256, 256, 0, stream>>>(G, W1, b1, dvec, nullptr, 1, sqv, Zh, Zl,
                                        nullptr, nullptr, nullptr, nullptr);
    k_scores<<<1024, 512, 0, stream>>>(Zh, Zl, sqv, pkey);
    k_merge<<<256, 256, 0, stream>>>(pkey, rowsumA, x, sval, sidx, d2vec, V, kp, sig);
    k_gemm_av<<<64 * ksplit, 256, 0, stream>>>(A, V, G, ksplit);
    if (ksplit == 4)
      k_lin<4><<<256, 256, 0, stream>>>(G, W2, b2, d2vec, (float*)d_out, 0, nullptr,
                                        nullptr, nullptr, V, sval, sidx, kp);
    else if (ksplit == 2)
      k_lin<2><<<256, 256, 0, stream>>>(G, W2, b2, d2vec, (float*)d_out, 0, nullptr,
                                        nullptr, nullptr, V, sval, sidx, kp);
    else
      k_lin<1><<<256, 256, 0, stream>>>(G, W2, b2, d2vec, (float*)d_out, 0, nullptr,
                                        nullptr, nullptr, V, sval, sidx, kp);
  }
}

// Round 7
// 209.743 us; speedup vs baseline: 3.7684x; 1.1111x over previous
//
#include <hip/hip_runtime.h>
#include <cstdint>
#include <cstddef>

#define NN 4096
#define DD 128

using short8 = __attribute__((ext_vector_type(8))) short;
using f32x4  = __attribute__((ext_vector_type(4))) float;
typedef unsigned long long u64;

typedef __attribute__((address_space(1))) void gvoid;
typedef __attribute__((address_space(3))) void lvoid;

__device__ __forceinline__ void async16(const void* g, void* l) {
  __builtin_amdgcn_global_load_lds((gvoid*)g, (lvoid*)l, 16, 0, 0);
}

__device__ __forceinline__ float dec_f(const void* p) {
  if (!p) return 1.0f;
  int b = *(const int*)p;
  return (b >= 0 && b < 1000000) ? (float)b : __int_as_float(b);
}
__device__ __forceinline__ int dec_i(const void* p) {
  if (!p) return 4;
  int b = *(const int*)p;
  return (b >= 0 && b < 1000000) ? b : (int)__int_as_float(b);
}

__device__ __forceinline__ unsigned short f2bf(float f) {
  union { float f; unsigned int u; } v; v.f = f;
  unsigned int u = v.u;
  unsigned int r = (u + 0x7fffu + ((u >> 16) & 1u)) >> 16;
  return (unsigned short)r;
}

// sorted-4 insert of packed key (d2_bits<<32 | idx), ascending
__device__ __forceinline__ void ins4(u64 (&l)[4], u64 k) {
#pragma unroll
  for (int t = 0; t < 4; ++t) {
    u64 old = l[t];
    bool bt = k < old;
    l[t] = bt ? k : old;
    k = bt ? old : k;
  }
}

// stage ROWS x KC bf16 tile (16B chunks; physical chunk p holds logical p^(r&7))
template <int ROWS, int KC, int NTHR>
__device__ __forceinline__ void stage2(const unsigned short* src, int row0, int kb,
                                       unsigned short* dst, int tid, int stride) {
  const int CPR = KC / 8;
  const int ITER = (ROWS * CPR) / NTHR;
#pragma unroll
  for (int t = 0; t < ITER; ++t) {
    int id = tid + t * NTHR;
    int r = id / CPR;
    int p = id % CPR;
    int lc = p ^ (r & 7);
    const void* g = src + (size_t)(row0 + r) * stride + kb + lc * 8;
    async16(g, dst + (size_t)(id & ~63) * 8);
  }
}

template <int CPR>
__device__ __forceinline__ short8 fragN(const unsigned short* t, int row, int ch) {
  return *(const short8*)(t + (size_t)(row * CPR + (ch ^ (row & 7))) * 8);
}

// ---------------- K1: rowsum(A), d = rsqrt, V = d*x, A -> bf16 ----------------
__global__ __launch_bounds__(256) void k_rowsum_scale(
    const float* __restrict__ A, const float* __restrict__ x,
    float* __restrict__ rowsumA, float* __restrict__ dvec, float* __restrict__ V,
    unsigned short* __restrict__ Ah) {
  int row = blockIdx.x;
  int tid = threadIdx.x;
  const float4* Arow = (const float4*)(A + (size_t)row * NN);
  float s = 0.f;
#pragma unroll
  for (int l = 0; l < 4; ++l) {
    int idx = tid + l * 256;
    float4 v = Arow[idx];
    s += (v.x + v.y) + (v.z + v.w);
    ushort4 h = {f2bf(v.x), f2bf(v.y), f2bf(v.z), f2bf(v.w)};
    *(ushort4*)(Ah + (size_t)row * NN + idx * 4) = h;
  }
  __shared__ float red[256];
  __shared__ float dsh;
  red[tid] = s;
  __syncthreads();
  if (tid < 64) {
    s = red[tid] + red[tid + 64] + red[tid + 128] + red[tid + 192];
#pragma unroll
    for (int off = 32; off > 0; off >>= 1) s += __shfl_down(s, off, 64);
    if (tid == 0) { rowsumA[row] = s; float d = rsqrtf(s); dvec[row] = d; dsh = d; }
  }
  __syncthreads();
  float d = dsh;
  if (tid < 32) {
    float4 xv = ((const float4*)(x + (size_t)row * DD))[tid];
    float4 o; o.x = d * xv.x; o.y = d * xv.y; o.z = d * xv.z; o.w = d * xv.w;
    ((float4*)(V + (size_t)row * DD))[tid] = o;
  }
}

// ---------------- K2: P = X @ W  (X [4096][128] fp32, W [128][128]) ----------------
__global__ __launch_bounds__(256) void k_xw(
    const float* __restrict__ X, const float* __restrict__ W, float* __restrict__ P) {
  int r0 = blockIdx.x * 16;
  int tid = threadIdx.x;
  int tr = tid >> 4, tc = tid & 15;
  __shared__ float Xs[16 * 132];
  __shared__ float Ws[32 * 128];
#pragma unroll
  for (int l = 0; l < 8; ++l) {
    int idx = tid + l * 256;
    int r = idx >> 7, c = idx & 127;
    Xs[r * 132 + c] = X[(size_t)(r0 + r) * DD + c];
  }
  float acc[8];
#pragma unroll
  for (int u = 0; u < 8; ++u) acc[u] = 0.f;
  for (int t0 = 0; t0 < 128; t0 += 32) {
    __syncthreads();
#pragma unroll
    for (int l = 0; l < 4; ++l) {
      int idx = tid + l * 256;
      int tt = idx >> 5, c4 = (idx & 31) << 2;
      *(float4*)(Ws + tt * 128 + c4) = *(const float4*)(W + (size_t)(t0 + tt) * DD + c4);
    }
    __syncthreads();
#pragma unroll 8
    for (int tt = 0; tt < 32; ++tt) {
      float g = Xs[tr * 132 + t0 + tt];
      float4 w0 = *(const float4*)(Ws + tt * 128 + tc * 8);
      float4 w1 = *(const float4*)(Ws + tt * 128 + tc * 8 + 4);
      acc[0] = fmaf(g, w0.x, acc[0]); acc[1] = fmaf(g, w0.y, acc[1]);
      acc[2] = fmaf(g, w0.z, acc[2]); acc[3] = fmaf(g, w0.w, acc[3]);
      acc[4] = fmaf(g, w1.x, acc[4]); acc[5] = fmaf(g, w1.y, acc[5]);
      acc[6] = fmaf(g, w1.z, acc[6]); acc[7] = fmaf(g, w1.w, acc[7]);
    }
  }
  size_t off = (size_t)(r0 + tr) * DD + tc * 8;
  float4 o0 = {acc[0], acc[1], acc[2], acc[3]};
  float4 o1 = {acc[4], acc[5], acc[6], acc[7]};
  *(float4*)(P + off) = o0;
  *(float4*)(P + off + 4) = o1;
}

// ---------------- K3: U [4096][128] fp32 -> UT [128][4096] bf16 ----------------
__global__ __launch_bounds__(256) void k_vt(
    const float* __restrict__ U, unsigned short* __restrict__ UTh) {
  __shared__ float Ls[64 * 132];
  int bx = blockIdx.x, tid = threadIdx.x;
  int r0 = bx * 64;
#pragma unroll
  for (int l = 0; l < 8; ++l) {
    int idx = tid + l * 256;
    int r = idx >> 5, c4 = (idx & 31) << 2;
    *(float4*)(Ls + r * 132 + c4) = *(const float4*)(U + (size_t)(r0 + r) * DD + c4);
  }
  __syncthreads();
  int c = tid >> 1, rh = tid & 1;
  unsigned short hb[32];
#pragma unroll
  for (int i = 0; i < 32; ++i) hb[i] = f2bf(Ls[(rh * 32 + i) * 132 + c]);
  size_t base = (size_t)c * NN + r0 + rh * 32;
#pragma unroll
  for (int q = 0; q < 8; ++q) {
    ushort4 h = {hb[q * 4], hb[q * 4 + 1], hb[q * 4 + 2], hb[q * 4 + 3]};
    *(ushort4*)(UTh + base + q * 4) = h;
  }
}

// ---------------- K4: MFMA bf16 GEMM  G_part = A[128 rows][KLEN k] @ U ----------------
template <int SPLIT>
__global__ __launch_bounds__(256) void k_gemm_bf16(
    const unsigned short* __restrict__ Ah, const unsigned short* __restrict__ Bh,
    float* __restrict__ G) {
  __shared__ __align__(16) unsigned short As_h[128 * 64];
  __shared__ __align__(16) unsigned short Bs_h[128 * 64];

  int bx = blockIdx.x;
  int mt = bx / SPLIT, sp = bx % SPLIT;
  int m0 = mt * 128;
  const int KLEN = NN / SPLIT;
  int ks = sp * KLEN;
  int tid = threadIdx.x, lane = tid & 63, w = tid >> 6;
  int wm = w >> 1, wn = w & 1;
  int l15 = lane & 15, quad = lane >> 4;

  f32x4 acc[4][4];
#pragma unroll
  for (int a = 0; a < 4; ++a)
#pragma unroll
    for (int b = 0; b < 4; ++b) acc[a][b] = (f32x4){0.f, 0.f, 0.f, 0.f};

  for (int kt = 0; kt < KLEN; kt += 64) {
    int kb = ks + kt;
    __syncthreads();
    stage2<128, 64, 256>(Ah, m0, kb, As_h, tid, NN);
    stage2<128, 64, 256>(Bh, 0, kb, Bs_h, tid, NN);
    __syncthreads();
#pragma unroll
    for (int k0 = 0; k0 < 64; k0 += 32) {
      int ch = (k0 >> 3) + quad;
      short8 a_h[4], b_h[4];
#pragma unroll
      for (int f = 0; f < 4; ++f) {
        a_h[f] = fragN<8>(As_h, wm * 64 + f * 16 + l15, ch);
        b_h[f] = fragN<8>(Bs_h, wn * 64 + f * 16 + l15, ch);
      }
#pragma unroll
      for (int fm = 0; fm < 4; ++fm)
#pragma unroll
        for (int fn = 0; fn < 4; ++fn)
          acc[fm][fn] = __builtin_amdgcn_mfma_f32_16x16x32_bf16(a_h[fm], b_h[fn], acc[fm][fn], 0, 0, 0);
    }
  }
  float* Gp = G + (size_t)sp * NN * DD;
#pragma unroll
  for (int fm = 0; fm < 4; ++fm) {
    int rb = m0 + wm * 64 + fm * 16 + quad * 4;
#pragma unroll
    for (int fn = 0; fn < 4; ++fn) {
      int c = wn * 64 + fn * 16 + l15;
#pragma unroll
      for (int i = 0; i < 4; ++i)
        Gp[(size_t)(rb + i) * DD + c] = acc[fm][fn][i];
    }
  }
}

// ---- K5: Out/Z = act( d * (sum_p G_p [+ sparse]) + b ); optional zh/sq emission ----
template <int NP>
__global__ __launch_bounds__(256) void k_red(
    const float* __restrict__ G, const float* __restrict__ dvec,
    const float* __restrict__ bvec, int leaky,
    float* __restrict__ Out, unsigned short* __restrict__ zh,
    float* __restrict__ sqout,
    const float* __restrict__ Usp, const float* __restrict__ sval,
    const int* __restrict__ sidx, const void* kptr) {
  int r0 = blockIdx.x * 16;
  int tid = threadIdx.x;
  int tr = tid >> 4, tc = tid & 15;
  int r = r0 + tr;
  size_t off = (size_t)r * DD + tc * 8;
  __shared__ float red[256];

  float acc[8];
#pragma unroll
  for (int u = 0; u < 8; ++u) acc[u] = 0.f;
#pragma unroll
  for (int p = 0; p < NP; ++p) {
    const float* gp = G + (size_t)p * NN * DD + off;
    float4 g0 = *(const float4*)gp;
    float4 g1 = *(const float4*)(gp + 4);
    acc[0] += g0.x; acc[1] += g0.y; acc[2] += g0.z; acc[3] += g0.w;
    acc[4] += g1.x; acc[5] += g1.y; acc[6] += g1.z; acc[7] += g1.w;
  }
  if (sidx != nullptr) {
    int kk = dec_i(kptr); kk = kk < 1 ? 1 : (kk > 4 ? 4 : kk);
    for (int t = 0; t < kk; ++t) {
      float sv = sval[r * 8 + t];
      int id = sidx[r * 8 + t];
      const float* vr = Usp + (size_t)id * DD + tc * 8;
      float4 w0 = *(const float4*)vr;
      float4 w1 = *(const float4*)(vr + 4);
      acc[0] = fmaf(sv, w0.x, acc[0]); acc[1] = fmaf(sv, w0.y, acc[1]);
      acc[2] = fmaf(sv, w0.z, acc[2]); acc[3] = fmaf(sv, w0.w, acc[3]);
      acc[4] = fmaf(sv, w1.x, acc[4]); acc[5] = fmaf(sv, w1.y, acc[5]);
      acc[6] = fmaf(sv, w1.z, acc[6]); acc[7] = fmaf(sv, w1.w, acc[7]);
    }
  }
  float d = dvec[r];
  float4 b0 = *(const float4*)(bvec + tc * 8);
  float4 b1 = *(const float4*)(bvec + tc * 8 + 4);
  float bb[8] = {b0.x, b0.y, b0.z, b0.w, b1.x, b1.y, b1.z, b1.w};
  float o[8];
#pragma unroll
  for (int u = 0; u < 8; ++u) {
    float v = fmaf(d, acc[u], bb[u]);
    if (leaky) v = v > 0.f ? v : 0.1f * v;
    o[u] = v;
  }
  if (Out) {
    float4 o0 = {o[0], o[1], o[2], o[3]};
    float4 o1 = {o[4], o[5], o[6], o[7]};
    *(float4*)(Out + off) = o0;
    *(float4*)(Out + off + 4) = o1;
  }
  if (zh) {
    ushort4 h0 = {f2bf(o[0]), f2bf(o[1]), f2bf(o[2]), f2bf(o[3])};
    ushort4 h1 = {f2bf(o[4]), f2bf(o[5]), f2bf(o[6]), f2bf(o[7])};
    *(ushort4*)(zh + off) = h0;
    *(ushort4*)(zh + off + 4) = h1;
  }
  if (sqout != nullptr) {
    float p = 0.f;
#pragma unroll
    for (int u = 0; u < 8; ++u) p = fmaf(o[u], o[u], p);
    red[tid] = p;
    __syncthreads();
    if (tc == 0) {
      float s = 0.f;
#pragma unroll
      for (int i = 0; i < 16; ++i) s += red[tr * 16 + i];
      sqout[r] = s;
    }
  }
}

// ---- K6: MFMA bf16 Z@Z^T, fused d2-key top-4 per (row, j-slice) ----
// grid 1024: mt (64 m-tiles of 64) x jp (16 j-slices of 256); block 512 (8 waves)
// LDS 32 KB -> 4 blocks/CU
__global__ __launch_bounds__(512, 8) void k_scores(
    const unsigned short* __restrict__ Zh,
    const float* __restrict__ sq, u64* __restrict__ pkey) {
  __shared__ __align__(16) unsigned short Am[64 * 128];   // 16 KB; merge lists alias
  __shared__ __align__(16) unsigned short Bj[64 * 128];   // 16 KB; Stile aliases
  float* Stile = (float*)&Bj[0];          // [64][64], XOR-swizzled float4 slots
  u64* mv = (u64*)&Am[0];                 // [512][4] packed keys (16 KB)

  int bx = blockIdx.x;
  int mt = bx >> 4, jp = bx & 15;
  int m0 = mt * 64, j0 = jp * 256;
  int tid = threadIdx.x, lane = tid & 63, w = tid >> 6;
  int wm = w >> 2, wn = w & 3;            // wave tile: 32 rows x 16 cols
  int l15 = lane & 15, quad = lane >> 4;

  stage2<64, 128, 512>(Zh, m0, 0, Am, tid, DD);

  int srow = tid >> 3;         // scan row 0..63
  int sc = tid & 7;            // scan col-octet
  float sqi_r = sq[m0 + srow];

  u64 lst[4];
#pragma unroll
  for (int s = 0; s < 4; ++s) lst[s] = ~0ull;

  for (int jt = 0; jt < 4; ++jt) {
    int jrow0 = j0 + jt * 64;
    __syncthreads();           // prev scan done (Stile = Bj about to be restaged)
    stage2<64, 128, 512>(Zh, jrow0, 0, Bj, tid, DD);
    __syncthreads();           // DMA visible (covers A on first iter)

    f32x4 acc[2];
    acc[0] = (f32x4){0.f, 0.f, 0.f, 0.f};
    acc[1] = (f32x4){0.f, 0.f, 0.f, 0.f};
#pragma unroll
    for (int kc = 0; kc < 4; ++kc) {
      int ch = kc * 4 + quad;
      short8 ah0 = fragN<16>(Am, wm * 32 + l15, ch);
      short8 ah1 = fragN<16>(Am, wm * 32 + 16 + l15, ch);
      short8 bh  = fragN<16>(Bj, wn * 16 + l15, ch);
      acc[0] = __builtin_amdgcn_mfma_f32_16x16x32_bf16(ah0, bh, acc[0], 0, 0, 0);
      acc[1] = __builtin_amdgcn_mfma_f32_16x16x32_bf16(ah1, bh, acc[1], 0, 0, 0);
    }
    __syncthreads();           // all Bj/Am frag reads done before Stile clobbers Bj

    // epilogue: Stile[r][c] = sqj - 2*dot, swizzled slot = (c>>2)^(r&7)
    {
      int c = wn * 16 + l15;
      float sqjv = sq[jrow0 + c];
      int cslot = c >> 2, cw = c & 3;
#pragma unroll
      for (int fm = 0; fm < 2; ++fm) {
        int rb = wm * 32 + fm * 16 + quad * 4;
#pragma unroll
        for (int i = 0; i < 4; ++i) {
          int r = rb + i;
          Stile[r * 64 + ((cslot ^ (r & 7)) << 2) + cw] = fmaf(-2.f, acc[fm][i], sqjv);
        }
      }
    }
    __syncthreads();           // Stile visible

    // scan: 8 threads/row, 8 cands each (2 swizzled float4 reads)
#pragma unroll
    for (int q = 0; q < 2; ++q) {
      int slot = sc * 2 + q;
      float4 kv = *(const float4*)(Stile + srow * 64 + ((slot ^ (srow & 7)) << 2));
      int jb = jrow0 + sc * 8 + q * 4;
      float ke[4] = {kv.x, kv.y, kv.z, kv.w};
#pragma unroll
      for (int e = 0; e < 4; ++e) {
        float v = fmaxf(sqi_r + ke[e], 0.f);
        ins4(lst, ((u64)__float_as_uint(v) << 32) | (unsigned)(jb + e));
      }
    }
  }

  __syncthreads();             // last scan + last Am frag reads done
#pragma unroll
  for (int s = 0; s < 4; ++s) mv[tid * 4 + s] = lst[s];
  __syncthreads();
  if (tid < 64) {
    u64 best[4] = {~0ull, ~0ull, ~0ull, ~0ull};
    for (int g = 0; g < 8; ++g) {
      int src = tid * 8 + g;
#pragma unroll
      for (int s = 0; s < 4; ++s) ins4(best, mv[src * 4 + s]);
    }
#pragma unroll
    for (int s = 0; s < 4; ++s)
      pkey[((size_t)(m0 + tid) * 16 + jp) * 4 + s] = best[s];
  }
}

// ---- K7: merge 16 partial key-lists, S, d2 = rsqrt(rowsumA + sum S), V = d2*x ----
__global__ __launch_bounds__(256) void k_merge(
    const u64* __restrict__ pkey,
    const float* __restrict__ rowsumA, const float* __restrict__ x,
    float* __restrict__ sval, int* __restrict__ sidx,
    float* __restrict__ d2vec, float* __restrict__ V,
    const void* kptr, const void* sigptr) {
  int bx = blockIdx.x;
  int r0 = bx * 16;
  int tid = threadIdx.x;
  int kk = dec_i(kptr); kk = kk < 1 ? 1 : (kk > 4 ? 4 : kk);
  float inv2s = 0.5f / dec_f(sigptr);
  __shared__ float ds[16];
  if (tid < 16) {
    int r = r0 + tid;
    u64 best[4] = {~0ull, ~0ull, ~0ull, ~0ull};
    for (int p = 0; p < 16; ++p) {
#pragma unroll
      for (int s = 0; s < 4; ++s) ins4(best, pkey[((size_t)r * 16 + p) * 4 + s]);
    }
    float srw = 0.f;
#pragma unroll
    for (int s = 0; s < 4; ++s) {
      if (s < kk) {
        float d2 = __uint_as_float((unsigned)(best[s] >> 32));
        float S = __expf(-sqrtf(d2 + 1e-10f) * inv2s);
        sval[r * 8 + s] = S;
        sidx[r * 8 + s] = (int)(best[s] & 0xffffffffu);
        srw += S;
      }
    }
    float dd = rsqrtf(rowsumA[r] + srw);
    d2vec[r] = dd;
    ds[tid] = dd;
  }
  __syncthreads();
#pragma unroll
  for (int l = 0; l < 2; ++l) {
    int idx = tid + l * 256;
    int rl = idx >> 5;
    int c4 = (idx & 31) << 2;
    float4 xv = *(const float4*)(x + (size_t)(r0 + rl) * DD + c4);
    float dd = ds[rl];
    float4 o; o.x = dd * xv.x; o.y = dd * xv.y; o.z = dd * xv.z; o.w = dd * xv.w;
    *(float4*)(V + (size_t)(r0 + rl) * DD + c4) = o;
  }
}

extern "C" void kernel_launch(void* const* d_in, const int* in_sizes, int n_in,
                              void* d_out, int out_size, void* d_ws, size_t ws_size,
                              hipStream_t stream) {
  const float* x  = (const float*)d_in[0];
  const float* A  = (const float*)d_in[1];
  const float* W1 = (const float*)d_in[2];
  const float* b1 = (const float*)d_in[3];
  const float* W2 = (const float*)d_in[4];
  const float* b2 = (const float*)d_in[5];
  const void* sig = (n_in > 6) ? d_in[6] : nullptr;
  const void* kp  = (n_in > 7) ? d_in[7] : nullptr;

  float* ws = (float*)d_ws;
  float* rowsumA = ws;                                   // 4096
  float* dvec    = ws + 4096;                            // 4096
  float* d2vec   = ws + 8192;                            // 4096
  float* sqv     = ws + 12288;                           // 4096
  float* sval    = ws + 16384;                           // 32768
  int*   sidx    = (int*)(ws + 49152);                   // 32768
  u64*   pkey    = (u64*)(ws + 81920);                   // 262144 u64 = 524288 floats
  unsigned short* Zh = (unsigned short*)(ws + 606208);   // 262144 floats
  float* V       = ws + 868352;                          // 524288
  float* U       = ws + 1392640;                         // 524288
  unsigned short* UTh = (unsigned short*)(ws + 1916928); // 262144 floats
  unsigned short* Ah  = (unsigned short*)(ws + 2179072); // 8388608 floats
  float* G       = ws + 10567680;                        // SPLIT * 524288

  const size_t F16 = 10567680 + 16 * 524288;  // ~75.8 MB
  int split16 = (ws_size >= F16 * 4);

  k_rowsum_scale<<<4096, 256, 0, stream>>>(A, x, rowsumA, dvec, V, Ah);
  // pass 1: Z = leaky(d * (A @ (V@W1)) + b1), emit Zh + sq
  k_xw<<<256, 256, 0, stream>>>(V, W1, U);
  k_vt<<<64, 256, 0, stream>>>(U, UTh);
  if (split16) {
    k_gemm_bf16<16><<<512, 256, 0, stream>>>(Ah, UTh, G);
    k_red<16><<<256, 256, 0, stream>>>(G, dvec, b1, 1, nullptr, Zh, sqv,
                                       nullptr, nullptr, nullptr, nullptr);
  } else {
    k_gemm_bf16<4><<<128, 256, 0, stream>>>(Ah, UTh, G);
    k_red<4><<<256, 256, 0, stream>>>(G, dvec, b1, 1, nullptr, Zh, sqv,
                                      nullptr, nullptr, nullptr, nullptr);
  }
  // scores + top-k
  k_scores<<<1024, 512, 0, stream>>>(Zh, sqv, pkey);
  k_merge<<<256, 256, 0, stream>>>(pkey, rowsumA, x, sval, sidx, d2vec, V, kp, sig);
  // pass 2: out = d2 * (A @ (V2@W2) + sparse) + b2
  k_xw<<<256, 256, 0, stream>>>(V, W2, U);
  k_vt<<<64, 256, 0, stream>>>(U, UTh);
  if (split16) {
    k_gemm_bf16<16><<<512, 256, 0, stream>>>(Ah, UTh, G);
    k_red<16><<<256, 256, 0, stream>>>(G, d2vec, b2, 0, (float*)d_out, nullptr, nullptr,
                                       U, sval, sidx, kp);
  } else {
    k_gemm_bf16<4><<<128, 256, 0, stream>>>(Ah, UTh, G);
    k_red<4><<<256, 256, 0, stream>>>(G, d2vec, b2, 0, (float*)d_out, nullptr, nullptr,
                                      U, sval, sidx, kp);
  }
}